// Round 1
// baseline (1464.748 us; speedup 1.0000x reference)
//
#include <hip/hip_runtime.h>
#include <cstddef>

#define SCALE 0.17677669529663687f
#define EPS 1e-5f

constexpr int BN_ = 128;
constexpr int BM_ = 96;
constexpr int CH_ = 4;
constexpr int BK_ = CH_ * 9;   // 36 phi-features per chunk

// ---------------- weight prep: Wc[k][o], k = c*9 + f (f=0 silu, f=1..8 rbf) ----
__global__ __launch_bounds__(256)
void prep_w(const float* __restrict__ wb, const float* __restrict__ ws,
            float* __restrict__ Wc, int M)
{
    int idx = blockIdx.x * 256 + threadIdx.x;
    if (idx >= 864 * M) return;
    int k = idx / M, o = idx - k * M;
    int c = k / 9, f = k - c * 9;
    Wc[idx] = (f == 0) ? wb[o * 96 + c] : ws[(o * 96 + c) * 8 + (f - 1)];
}

// ---------------- fused-phi KAN GEMM -----------------------------------------
// out rows M, cols N (positions). Input gathered per column as (ptr, stride).
// WINDOWED: col p -> window w=p/17, l=p%17; l==0 -> group token.
template<int M, int LIN, int OUTL, bool WINDOWED>
__global__ __launch_bounds__(256)
void kan_gemm(const float* __restrict__ in, const float* __restrict__ token,
              const float* __restrict__ Wc, float* __restrict__ out)
{
    __shared__ float sW[BK_][BM_];   // k-major weight tile
    __shared__ float sP[BK_][BN_];   // phi tile

    int tid = threadIdx.x;
    int n0 = blockIdx.x * BN_;
    int m0 = blockIdx.y * BM_;

    // per-thread gather column (2 threads per column)
    int col = tid & 127;
    int p = n0 + col;
    const float* myPtr;
    int myStride;
    if (WINDOWED) {
        int w = p / 17, l = p - w * 17;
        if (l == 0) { myPtr = token; myStride = 1; }
        else {
            int b = w >> 6, wl = w & 63;
            int wx = wl >> 3, wy = wl & 7;
            int j = l - 1, gx = j >> 2, gy = j & 3;
            myPtr = in + (size_t)b * 98304 + (wx * 4 + gx) * 32 + wy * 4 + gy;
            myStride = 1024;
        }
    } else {
        int nb = p / LIN, l = p - nb * LIN;
        myPtr = in + (size_t)nb * (96 * LIN) + l;
        myStride = LIN;
    }

    int tx = tid & 15, ty = tid >> 4;
    float acc[6][8] = {};

    for (int ch = 0; ch < 96; ch += CH_) {
        __syncthreads();
        // stage W tile (float4)
        for (int idx = tid; idx < BK_ * BM_ / 4; idx += 256) {
            int kk = idx / (BM_ / 4), mm = idx - kk * (BM_ / 4);
            reinterpret_cast<float4*>(sW[kk])[mm] =
                reinterpret_cast<const float4*>(Wc + (size_t)(ch * 9 + kk) * M + m0)[mm];
        }
        // load x, compute phi into LDS
        #pragma unroll
        for (int it = 0; it < 2; ++it) {
            int cc = (tid + it * 256) >> 7;  // 0..3
            float x = myPtr[(ch + cc) * myStride];
            float s = x / (1.f + __expf(-x));      // silu
            sP[cc * 9][col] = s;
            #pragma unroll
            for (int g = 0; g < 8; ++g) {
                float t = (x - (-2.f + g * (4.f / 7.f))) * 1.75f;
                sP[cc * 9 + 1 + g][col] = __expf(-t * t);
            }
        }
        __syncthreads();
        #pragma unroll 6
        for (int k = 0; k < BK_; ++k) {
            float a[6], bb[8];
            #pragma unroll
            for (int j = 0; j < 6; ++j) a[j] = sW[k][ty + j * 16];
            #pragma unroll
            for (int i = 0; i < 8; ++i) bb[i] = sP[k][tx + i * 16];
            #pragma unroll
            for (int j = 0; j < 6; ++j)
                #pragma unroll
                for (int i = 0; i < 8; ++i)
                    acc[j][i] += a[j] * bb[i];
        }
    }

    size_t outBase = (size_t)(n0 / OUTL) * ((size_t)M * OUTL) + (size_t)(n0 % OUTL);
    #pragma unroll
    for (int j = 0; j < 6; ++j) {
        size_t rowOff = outBase + (size_t)(m0 + ty + j * 16) * OUTL + tx;
        #pragma unroll
        for (int i = 0; i < 8; ++i)
            out[rowOff + i * 16] = acc[j][i];
    }
}

// ---------------- window feature-attention (32x32, contract 17 tokens) -------
__global__ __launch_bounds__(256)
void attn1(const float* __restrict__ qkv, float* __restrict__ gt, float* __restrict__ gf)
{
    int w = blockIdx.x;            // 8192 windows
    int tid = threadIdx.x;
    __shared__ float sq[3][32][17];
    __shared__ float sk[3][32][17];
    __shared__ float sv[3][32][17];
    __shared__ float sa[3][32][33];   // attn, padded
    const size_t N = 139264;

    for (int e = tid; e < 288 * 17; e += 256) {
        int row = e / 17, l = e - row * 17;
        float v = qkv[(size_t)row * N + (size_t)w * 17 + l];
        int sec = row / 96, ch = row - sec * 96;
        int h = ch >> 5, d = ch & 31;
        if (sec == 0)      sq[h][d][l] = v * SCALE;
        else if (sec == 1) sk[h][d][l] = v;
        else               sv[h][d][l] = v;
    }
    __syncthreads();
    // dots[h][i][j] = sum_l q[h][i][l] * k[h][j][l]
    for (int e = tid; e < 3 * 32 * 32; e += 256) {
        int h = e >> 10, r = e & 1023, i = r >> 5, j = r & 31;
        float s = 0.f;
        #pragma unroll
        for (int l = 0; l < 17; ++l) s += sq[h][i][l] * sk[h][j][l];
        sa[h][i][j] = s;
    }
    __syncthreads();
    if (tid < 96) {
        int h = tid >> 5, i = tid & 31;
        float m = -1e30f;
        for (int j = 0; j < 32; ++j) m = fmaxf(m, sa[h][i][j]);
        float sum = 0.f;
        for (int j = 0; j < 32; ++j) { float e_ = __expf(sa[h][i][j] - m); sa[h][i][j] = e_; sum += e_; }
        float inv = 1.f / sum;
        for (int j = 0; j < 32; ++j) sa[h][i][j] *= inv;
    }
    __syncthreads();
    int b = w >> 6, wl = w & 63;
    // out[h][l][i] = sum_j attn[h][i][j] * v[h][j][l]
    for (int e = tid; e < 3 * 17 * 32; e += 256) {
        int h = e / 544, r = e - h * 544, l = r >> 5, i = r & 31;
        float s = 0.f;
        #pragma unroll
        for (int j = 0; j < 32; ++j) s += sa[h][i][j] * sv[h][j][l];
        if (l == 0) gt[(((size_t)b * 3 + h) * 64 + wl) * 32 + i] = s;
        else        gf[((((size_t)b * 3 + h) * 64 + wl) * 16 + (l - 1)) * 32 + i] = s;
    }
}

// ---------------- LN (over 32) + exact GELU -> hh (b, 96, 64) ----------------
__global__ __launch_bounds__(256)
void ln_gelu(const float* __restrict__ gt, const float* __restrict__ lng,
             const float* __restrict__ lnb, float* __restrict__ hh)
{
    int row = blockIdx.x * 8 + (threadIdx.x >> 5);   // (b*3+h)*64+wl, 24576 rows
    int d = threadIdx.x & 31;
    float x = gt[(size_t)row * 32 + d];
    float s = x, s2 = x * x;
    #pragma unroll
    for (int m = 16; m >= 1; m >>= 1) { s += __shfl_xor(s, m, 32); s2 += __shfl_xor(s2, m, 32); }
    float mu = s * (1.f / 32.f);
    float var = s2 * (1.f / 32.f) - mu * mu;
    float h = (x - mu) * rsqrtf(var + EPS) * lng[d] + lnb[d];
    float g = 0.5f * h * (1.f + erff(h * 0.70710678118654752f));
    int b = row / 192, r = row - b * 192;
    int hd = r >> 6, wl = r & 63;
    hh[((size_t)b * 96 + hd * 32 + d) * 64 + wl] = g;
}

// ---------------- window-token attention: dots + softmax ---------------------
__global__ __launch_bounds__(256)
void attn2a(const float* __restrict__ qk, float* __restrict__ wattn)
{
    int bh = blockIdx.x;            // 384 = b*3+h
    int b = bh / 3, h = bh - b * 3;
    __shared__ float swq[64][33];
    __shared__ float swk[64][33];
    __shared__ float sd[64][65];
    int tid = threadIdx.x;
    for (int e = tid; e < 2048; e += 256) {
        int d = e >> 6, i = e & 63;
        swq[i][d] = qk[((size_t)h * 64 + d) * 8192 + b * 64 + i] * SCALE;
        swk[i][d] = qk[((size_t)h * 64 + 32 + d) * 8192 + b * 64 + i];
    }
    __syncthreads();
    for (int e = tid; e < 4096; e += 256) {
        int i = e >> 6, j = e & 63;
        float s = 0.f;
        #pragma unroll
        for (int d = 0; d < 32; ++d) s += swq[i][d] * swk[j][d];
        sd[i][j] = s;
    }
    __syncthreads();
    if (tid < 64) {
        float m = -1e30f;
        for (int j = 0; j < 64; ++j) m = fmaxf(m, sd[tid][j]);
        float sum = 0.f;
        for (int j = 0; j < 64; ++j) { float e_ = __expf(sd[tid][j] - m); sd[tid][j] = e_; sum += e_; }
        float inv = 1.f / sum;
        for (int j = 0; j < 64; ++j) sd[tid][j] *= inv;
    }
    __syncthreads();
    for (int e = tid; e < 4096; e += 256)
        wattn[(size_t)bh * 4096 + e] = sd[e >> 6][e & 63];
}

// ---------------- agg = attn @ gf, scatter to fmap (b,96,32,32) --------------
__global__ __launch_bounds__(256)
void attn2b(const float* __restrict__ wattn, const float* __restrict__ gf,
            float* __restrict__ fmap)
{
    int blk = blockIdx.x;           // 1536 = bh*4 + ct  (ct == gx)
    int ct = blk & 3, bh = blk >> 2;
    int b = bh / 3, h = bh - b * 3;
    __shared__ float sa[64][65];
    __shared__ float sg[64][129];
    int tid = threadIdx.x;
    for (int e = tid; e < 4096; e += 256) sa[e >> 6][e & 63] = wattn[(size_t)bh * 4096 + e];
    for (int e = tid; e < 8192; e += 256) {
        int j = e >> 7, c = e & 127;
        sg[j][c] = gf[((size_t)bh * 64 + j) * 512 + ct * 128 + c];
    }
    __syncthreads();
    int txc = tid & 31, tyi = tid >> 5;
    float acc[8][4];
    #pragma unroll
    for (int ii = 0; ii < 8; ++ii)
        #pragma unroll
        for (int c = 0; c < 4; ++c) acc[ii][c] = 0.f;
    for (int j = 0; j < 64; ++j) {
        float g0[4];
        #pragma unroll
        for (int c = 0; c < 4; ++c) g0[c] = sg[j][txc + c * 32];
        #pragma unroll
        for (int ii = 0; ii < 8; ++ii) {
            float a = sa[tyi + ii * 8][j];
            #pragma unroll
            for (int c = 0; c < 4; ++c) acc[ii][c] += a * g0[c];
        }
    }
    __syncthreads();
    #pragma unroll
    for (int ii = 0; ii < 8; ++ii)
        #pragma unroll
        for (int c = 0; c < 4; ++c)
            sg[tyi + ii * 8][txc + c * 32] = acc[ii][c];
    __syncthreads();
    // coalesced fmap write: e = d(32) x nx(8) x (ny*4+gy)(32)
    for (int e = tid; e < 8192; e += 256) {
        int d = e >> 8;
        int nx = (e >> 5) & 7;
        int cp = e & 31;
        int ny = cp >> 2, gy = cp & 3;
        float v = sg[nx * 8 + ny][gy * 32 + d];
        fmap[(((size_t)b * 96 + h * 32 + d) * 32 + nx * 4 + ct) * 32 + cp] = v;
    }
}

// -----------------------------------------------------------------------------
extern "C" void kernel_launch(void* const* d_in, const int* in_sizes, int n_in,
                              void* d_out, int out_size, void* d_ws, size_t ws_size,
                              hipStream_t stream)
{
    const float* x      = (const float*)d_in[0];
    const float* tok    = (const float*)d_in[1];
    const float* qkv_wb = (const float*)d_in[2];
    const float* qkv_ws = (const float*)d_in[3];
    const float* lng    = (const float*)d_in[4];
    const float* lnb    = (const float*)d_in[5];
    const float* gt_wb  = (const float*)d_in[6];
    const float* gt_ws  = (const float*)d_in[7];
    const float* out_wb = (const float*)d_in[8];
    const float* out_ws = (const float*)d_in[9];
    float* out = (float*)d_out;
    float* ws  = (float*)d_ws;

    // workspace layout (floats); fmap & wattn reuse the dead qkv region
    const size_t OFF_QKV   = 0;            // 40,108,032
    const size_t OFF_FMAP  = 0;            // 12,582,912 (after qkv dead)
    const size_t OFF_WATTN = 12582912;     // 1,572,864
    const size_t OFF_WC1   = 40108032;
    const size_t OFF_WC2   = OFF_WC1 + 248832;
    const size_t OFF_WC3   = OFF_WC2 + 165888;
    const size_t OFF_GT    = OFF_WC3 + 82944;
    const size_t OFF_GF    = OFF_GT + 786432;
    const size_t OFF_HH    = OFF_GF + 12582912;
    const size_t OFF_QK    = OFF_HH + 786432;
    const size_t TOTAL     = OFF_QK + 1572864;   // 56,334,336 floats = 225.3 MB
    if (ws_size < TOTAL * sizeof(float)) return; // ws too small -> fail loudly

    prep_w<<<972, 256, 0, stream>>>(qkv_wb, qkv_ws, ws + OFF_WC1, 288);
    prep_w<<<648, 256, 0, stream>>>(gt_wb,  gt_ws,  ws + OFF_WC2, 192);
    prep_w<<<324, 256, 0, stream>>>(out_wb, out_ws, ws + OFF_WC3, 96);

    kan_gemm<288, 17, 139264, true ><<<dim3(1088, 3), 256, 0, stream>>>(x, tok, ws + OFF_WC1, ws + OFF_QKV);
    attn1<<<8192, 256, 0, stream>>>(ws + OFF_QKV, ws + OFF_GT, ws + OFF_GF);
    ln_gelu<<<3072, 256, 0, stream>>>(ws + OFF_GT, lng, lnb, ws + OFF_HH);
    kan_gemm<192, 64, 8192, false><<<dim3(64, 2), 256, 0, stream>>>(ws + OFF_HH, nullptr, ws + OFF_WC2, ws + OFF_QK);
    attn2a<<<384, 256, 0, stream>>>(ws + OFF_QK, ws + OFF_WATTN);
    attn2b<<<1536, 256, 0, stream>>>(ws + OFF_WATTN, ws + OFF_GF, ws + OFF_FMAP);
    kan_gemm<96, 1024, 1024, false><<<dim3(1024, 1), 256, 0, stream>>>(ws + OFF_FMAP, nullptr, ws + OFF_WC3, out);
}

// Round 4
// 689.815 us; speedup vs baseline: 2.1234x; 2.1234x over previous
//
#include <hip/hip_runtime.h>
#include <cstddef>

#define SCALE 0.17677669529663687f
#define EPS 1e-5f

typedef __attribute__((ext_vector_type(8))) __bf16 bf16x8;
typedef __attribute__((ext_vector_type(4))) float f32x4;
typedef __attribute__((ext_vector_type(8))) unsigned short ushort8;

__device__ __forceinline__ unsigned short f2bf(float f) {
    unsigned u = __float_as_uint(f);
    return (unsigned short)((u + 0x7fffu + ((u >> 16) & 1u)) >> 16);
}
__device__ __forceinline__ float bf2f(unsigned short h) {
    return __uint_as_float(((unsigned)h) << 16);
}

#define GLD_LDS16(gsrc, ldst) \
    __builtin_amdgcn_global_load_lds((const __attribute__((address_space(1))) void*)(gsrc), \
                                     (__attribute__((address_space(3))) void*)(ldst), 16, 0, 0)

// ============ prep: pack W into MFMA A-fragments, split hi/lo bf16 ============
// K-order: step s = f*3+cg covers feature f=s/3, channels cg*32..+31.
// Frag layout per step: frag id = mt*2+h (h=0 hi, 1 lo), 1024B lane-linear:
// lane l slot holds W[m = mt*16+(l&15)][k-slot j], c = cg*32+(l>>4)*8+j.
__global__ __launch_bounds__(256)
void prep_frag(const float* __restrict__ wb, const float* __restrict__ ws,
               unsigned short* __restrict__ Wf, int MT16)
{
    int idx = blockIdx.x * 256 + threadIdx.x;
    int total = 27 * MT16 * 64;
    if (idx >= total) return;
    int lane = idx & 63;
    int t = idx >> 6;
    int mt = t % MT16;
    int s = t / MT16;
    int f = s / 3, cg = s - f * 3;
    int m = mt * 16 + (lane & 15);
    ushort8 hv, lv;
    #pragma unroll
    for (int j = 0; j < 8; ++j) {
        int c = cg * 32 + (lane >> 4) * 8 + j;
        float w = (f == 0) ? wb[m * 96 + c] : ws[(m * 96 + c) * 8 + (f - 1)];
        unsigned short hi = f2bf(w);
        unsigned short lo = f2bf(w - bf2f(hi));
        hv[j] = hi; lv[j] = lo;
    }
    size_t base = (size_t)((s * MT16 + mt) * 2) * 512 + lane * 8;
    *reinterpret_cast<ushort8*>(Wf + base) = hv;
    *reinterpret_cast<ushort8*>(Wf + base + 512) = lv;
}

// ---------------- phi generation: 8 values -> one hi frag slot + one lo ------
template<int CG>
__device__ __forceinline__ void phi_gen(const float (&xr)[24], int f,
                                        char* sBh, char* sBl, int lane)
{
    ushort8 hv, lv;
    float center = -2.f + (f - 1) * (4.f / 7.f);
    #pragma unroll
    for (int j = 0; j < 8; ++j) {
        float xv = xr[CG * 8 + j];
        float ph;
        if (f == 0) ph = xv / (1.f + __expf(-xv));
        else { float t = (xv - center) * 1.75f; ph = __expf(-t * t); }
        unsigned short hi = f2bf(ph);
        unsigned short lo = f2bf(ph - bf2f(hi));
        hv[j] = hi; lv[j] = lo;
    }
    *reinterpret_cast<ushort8*>(sBh + lane * 16) = hv;
    *reinterpret_cast<ushort8*>(sBl + lane * 16) = lv;
}

template<int MT>
__device__ __forceinline__ void mfma_step(const char* sAp, const char* sBp,
                                          f32x4 (&acc)[MT][2], int lane, int wm, int wn)
{
    bf16x8 bfr[2][2];
    #pragma unroll
    for (int nt = 0; nt < 2; ++nt)
        #pragma unroll
        for (int h = 0; h < 2; ++h)
            bfr[nt][h] = *reinterpret_cast<const bf16x8*>(
                sBp + (((wn * 2 + nt) * 2 + h) * 1024) + lane * 16);
    #pragma unroll
    for (int mt = 0; mt < MT; ++mt) {
        bf16x8 ah = *reinterpret_cast<const bf16x8*>(
            sAp + (((wm * MT + mt) * 2 + 0) * 1024) + lane * 16);
        bf16x8 al = *reinterpret_cast<const bf16x8*>(
            sAp + (((wm * MT + mt) * 2 + 1) * 1024) + lane * 16);
        #pragma unroll
        for (int nt = 0; nt < 2; ++nt) {
            acc[mt][nt] = __builtin_amdgcn_mfma_f32_16x16x32_bf16(ah, bfr[nt][0], acc[mt][nt], 0, 0, 0);
            acc[mt][nt] = __builtin_amdgcn_mfma_f32_16x16x32_bf16(ah, bfr[nt][1], acc[mt][nt], 0, 0, 0);
            acc[mt][nt] = __builtin_amdgcn_mfma_f32_16x16x32_bf16(al, bfr[nt][0], acc[mt][nt], 0, 0, 0);
        }
    }
}

// ============ fused-phi split-bf16 MFMA KAN GEMM =============================
// MODE 0: windowed gather (L1, out [M][139264]);  MODE 1: fmap (L3, out [b][M][1024])
template<int M, int MODE>
__global__ __launch_bounds__(512, 2)
void kan_mfma(const float* __restrict__ xin, const float* __restrict__ token,
              const unsigned short* __restrict__ Wf, float* __restrict__ out)
{
    constexpr int MT16 = M / 16;
    constexpr int NF = MT16 * 2;      // A frags per step (hi+lo)
    constexpr int MT = MT16 / 2;      // per-wave m-tiles (wave grid 2x4)
    __shared__ char sA[2 * NF * 1024];
    __shared__ char sB[2 * 16 * 1024];

    const int tid = threadIdx.x, lane = tid & 63, wid = tid >> 6;
    const int wm = wid >> 2, wn = wid & 3;
    const int n0 = blockIdx.x * 128;

    auto issueA = [&](int s, int buf) {
        for (int c = wid; c < NF; c += 8) {
            const unsigned short* src = Wf + (size_t)(s * NF + c) * 512 + lane * 8;
            char* dst = sA + (buf * NF + c) * 1024;
            GLD_LDS16(src, dst);
        }
    };
    issueA(0, 0);

    // ---- gather the 24 x-values this thread contributes to phi -------------
    const int mycol = wid * 16 + (lane & 15);
    const int p = n0 + mycol;
    const float* gbase;
    int gstride;
    if (MODE == 0) {
        int w = p / 17, l = p - w * 17;
        if (l == 0) { gbase = token; gstride = 1; }
        else {
            int b = w >> 6, wl = w & 63;
            int wx = wl >> 3, wy = wl & 7;
            int jj = l - 1, gx = jj >> 2, gy = jj & 3;
            gbase = xin + (size_t)b * 98304 + (wx * 4 + gx) * 32 + wy * 4 + gy;
            gstride = 1024;
        }
    } else {
        gbase = xin + (size_t)(p >> 10) * 98304 + (p & 1023);
        gstride = 1024;
    }
    const int g8 = (lane >> 4) * 8;
    float xr[24];
    #pragma unroll
    for (int cg = 0; cg < 3; ++cg)
        #pragma unroll
        for (int j = 0; j < 8; ++j)
            xr[cg * 8 + j] = gbase[(size_t)(cg * 32 + g8 + j) * gstride];

    f32x4 acc[MT][2];
    #pragma unroll
    for (int mt = 0; mt < MT; ++mt)
        #pragma unroll
        for (int nt = 0; nt < 2; ++nt) {
            f32x4 z = {0.f, 0.f, 0.f, 0.f};
            acc[mt][nt] = z;
        }

    // phi for s=0 (f=0, cg=0) into sB buffer 0
    phi_gen<0>(xr, 0, sB + (wid * 2 + 0) * 1024, sB + (wid * 2 + 1) * 1024, lane);

#define STEP(CG) {                                                              \
        const int s_ = f * 3 + CG;                                              \
        const int sbuf_ = s_ & 1;                                               \
        __syncthreads();                                                        \
        if (s_ + 1 < 27) issueA(s_ + 1, (s_ + 1) & 1);                          \
        mfma_step<MT>(sA + sbuf_ * NF * 1024, sB + sbuf_ * 16 * 1024,           \
                      acc, lane, wm, wn);                                       \
        if (s_ + 1 < 27)                                                        \
            phi_gen<(CG + 1) % 3>(xr, (CG == 2) ? f + 1 : f,                    \
                sB + (((sbuf_ ^ 1) * 16 + wid * 2 + 0) * 1024),                 \
                sB + (((sbuf_ ^ 1) * 16 + wid * 2 + 1) * 1024), lane);          \
    }

    for (int f = 0; f < 9; ++f) { STEP(0) STEP(1) STEP(2) }
#undef STEP

    // ---- epilogue ----
    #pragma unroll
    for (int mt = 0; mt < MT; ++mt) {
        const int row = wm * (M / 2) + mt * 16 + (lane >> 4) * 4;
        #pragma unroll
        for (int nt = 0; nt < 2; ++nt) {
            const int col_l = wn * 32 + nt * 16 + (lane & 15);
            #pragma unroll
            for (int r = 0; r < 4; ++r) {
                float v = acc[mt][nt][r];
                if (MODE == 0)
                    out[(size_t)(row + r) * 139264 + n0 + col_l] = v;
                else {
                    int col = n0 + col_l;
                    out[(size_t)(col >> 10) * 98304 + (size_t)(row + r) * 1024 + (col & 1023)] = v;
                }
            }
        }
    }
}

// ---------------- weight prep for L2 (fp32 path): Wc[k][o], k=c*9+f ----------
__global__ __launch_bounds__(256)
void prep_w(const float* __restrict__ wb, const float* __restrict__ ws,
            float* __restrict__ Wc, int M)
{
    int idx = blockIdx.x * 256 + threadIdx.x;
    if (idx >= 864 * M) return;
    int k = idx / M, o = idx - k * M;
    int c = k / 9, f = k - c * 9;
    Wc[idx] = (f == 0) ? wb[o * 96 + c] : ws[(o * 96 + c) * 8 + (f - 1)];
}

// ---------------- fp32 fused-phi KAN GEMM (kept for L2) ----------------------
constexpr int BN_ = 128;
constexpr int BM_ = 96;
constexpr int CH_ = 4;
constexpr int BK_ = CH_ * 9;

template<int M, int LIN, int OUTL, bool WINDOWED>
__global__ __launch_bounds__(256)
void kan_gemm(const float* __restrict__ in, const float* __restrict__ token,
              const float* __restrict__ Wc, float* __restrict__ out)
{
    __shared__ float sW[BK_][BM_];
    __shared__ float sP[BK_][BN_];

    int tid = threadIdx.x;
    int n0 = blockIdx.x * BN_;
    int m0 = blockIdx.y * BM_;

    int col = tid & 127;
    int p = n0 + col;
    const float* myPtr;
    int myStride;
    if (WINDOWED) {
        int w = p / 17, l = p - w * 17;
        if (l == 0) { myPtr = token; myStride = 1; }
        else {
            int b = w >> 6, wl = w & 63;
            int wx = wl >> 3, wy = wl & 7;
            int j = l - 1, gx = j >> 2, gy = j & 3;
            myPtr = in + (size_t)b * 98304 + (wx * 4 + gx) * 32 + wy * 4 + gy;
            myStride = 1024;
        }
    } else {
        int nb = p / LIN, l = p - nb * LIN;
        myPtr = in + (size_t)nb * (96 * LIN) + l;
        myStride = LIN;
    }

    int tx = tid & 15, ty = tid >> 4;
    float acc[6][8] = {};

    for (int ch = 0; ch < 96; ch += CH_) {
        __syncthreads();
        for (int idx = tid; idx < BK_ * BM_ / 4; idx += 256) {
            int kk = idx / (BM_ / 4), mm = idx - kk * (BM_ / 4);
            reinterpret_cast<float4*>(sW[kk])[mm] =
                reinterpret_cast<const float4*>(Wc + (size_t)(ch * 9 + kk) * M + m0)[mm];
        }
        #pragma unroll
        for (int it = 0; it < 2; ++it) {
            int cc = (tid + it * 256) >> 7;
            float x = myPtr[(ch + cc) * myStride];
            float s = x / (1.f + __expf(-x));
            sP[cc * 9][col] = s;
            #pragma unroll
            for (int g = 0; g < 8; ++g) {
                float t = (x - (-2.f + g * (4.f / 7.f))) * 1.75f;
                sP[cc * 9 + 1 + g][col] = __expf(-t * t);
            }
        }
        __syncthreads();
        #pragma unroll 6
        for (int k = 0; k < BK_; ++k) {
            float a[6], bb[8];
            #pragma unroll
            for (int j = 0; j < 6; ++j) a[j] = sW[k][ty + j * 16];
            #pragma unroll
            for (int i = 0; i < 8; ++i) bb[i] = sP[k][tx + i * 16];
            #pragma unroll
            for (int j = 0; j < 6; ++j)
                #pragma unroll
                for (int i = 0; i < 8; ++i)
                    acc[j][i] += a[j] * bb[i];
        }
    }

    size_t outBase = (size_t)(n0 / OUTL) * ((size_t)M * OUTL) + (size_t)(n0 % OUTL);
    #pragma unroll
    for (int j = 0; j < 6; ++j) {
        size_t rowOff = outBase + (size_t)(m0 + ty + j * 16) * OUTL + tx;
        #pragma unroll
        for (int i = 0; i < 8; ++i)
            out[rowOff + i * 16] = acc[j][i];
    }
}

// ---------------- window feature-attention (32x32, contract 17 tokens) -------
__global__ __launch_bounds__(256)
void attn1(const float* __restrict__ qkv, float* __restrict__ gt, float* __restrict__ gf)
{
    int w = blockIdx.x;
    int tid = threadIdx.x;
    __shared__ float sq[3][32][17];
    __shared__ float sk[3][32][17];
    __shared__ float sv[3][32][17];
    __shared__ float sa[3][32][33];
    const size_t N = 139264;

    for (int e = tid; e < 288 * 17; e += 256) {
        int row = e / 17, l = e - row * 17;
        float v = qkv[(size_t)row * N + (size_t)w * 17 + l];
        int sec = row / 96, ch = row - sec * 96;
        int h = ch >> 5, d = ch & 31;
        if (sec == 0)      sq[h][d][l] = v * SCALE;
        else if (sec == 1) sk[h][d][l] = v;
        else               sv[h][d][l] = v;
    }
    __syncthreads();
    for (int e = tid; e < 3 * 32 * 32; e += 256) {
        int h = e >> 10, r = e & 1023, i = r >> 5, j = r & 31;
        float s = 0.f;
        #pragma unroll
        for (int l = 0; l < 17; ++l) s += sq[h][i][l] * sk[h][j][l];
        sa[h][i][j] = s;
    }
    __syncthreads();
    if (tid < 96) {
        int h = tid >> 5, i = tid & 31;
        float m = -1e30f;
        for (int j = 0; j < 32; ++j) m = fmaxf(m, sa[h][i][j]);
        float sum = 0.f;
        for (int j = 0; j < 32; ++j) { float e_ = __expf(sa[h][i][j] - m); sa[h][i][j] = e_; sum += e_; }
        float inv = 1.f / sum;
        for (int j = 0; j < 32; ++j) sa[h][i][j] *= inv;
    }
    __syncthreads();
    int b = w >> 6, wl = w & 63;
    for (int e = tid; e < 3 * 17 * 32; e += 256) {
        int h = e / 544, r = e - h * 544, l = r >> 5, i = r & 31;
        float s = 0.f;
        #pragma unroll
        for (int j = 0; j < 32; ++j) s += sa[h][i][j] * sv[h][j][l];
        if (l == 0) gt[(((size_t)b * 3 + h) * 64 + wl) * 32 + i] = s;
        else        gf[((((size_t)b * 3 + h) * 64 + wl) * 16 + (l - 1)) * 32 + i] = s;
    }
}

// ---------------- LN (over 32) + exact GELU -> hh (b, 96, 64) ----------------
__global__ __launch_bounds__(256)
void ln_gelu(const float* __restrict__ gt, const float* __restrict__ lng,
             const float* __restrict__ lnb, float* __restrict__ hh)
{
    int row = blockIdx.x * 8 + (threadIdx.x >> 5);
    int d = threadIdx.x & 31;
    float x = gt[(size_t)row * 32 + d];
    float s = x, s2 = x * x;
    #pragma unroll
    for (int m = 16; m >= 1; m >>= 1) { s += __shfl_xor(s, m, 32); s2 += __shfl_xor(s2, m, 32); }
    float mu = s * (1.f / 32.f);
    float var = s2 * (1.f / 32.f) - mu * mu;
    float h = (x - mu) * rsqrtf(var + EPS) * lng[d] + lnb[d];
    float g = 0.5f * h * (1.f + erff(h * 0.70710678118654752f));
    int b = row / 192, r = row - b * 192;
    int hd = r >> 6, wl = r & 63;
    hh[((size_t)b * 96 + hd * 32 + d) * 64 + wl] = g;
}

// ---------------- window-token attention: dots + softmax ---------------------
__global__ __launch_bounds__(256)
void attn2a(const float* __restrict__ qk, float* __restrict__ wattn)
{
    int bh = blockIdx.x;
    int b = bh / 3, h = bh - b * 3;
    __shared__ float swq[64][33];
    __shared__ float swk[64][33];
    __shared__ float sd[64][65];
    int tid = threadIdx.x;
    for (int e = tid; e < 2048; e += 256) {
        int d = e >> 6, i = e & 63;
        swq[i][d] = qk[((size_t)h * 64 + d) * 8192 + b * 64 + i] * SCALE;
        swk[i][d] = qk[((size_t)h * 64 + 32 + d) * 8192 + b * 64 + i];
    }
    __syncthreads();
    for (int e = tid; e < 4096; e += 256) {
        int i = e >> 6, j = e & 63;
        float s = 0.f;
        #pragma unroll
        for (int d = 0; d < 32; ++d) s += swq[i][d] * swk[j][d];
        sd[i][j] = s;
    }
    __syncthreads();
    if (tid < 64) {
        float m = -1e30f;
        for (int j = 0; j < 64; ++j) m = fmaxf(m, sd[tid][j]);
        float sum = 0.f;
        for (int j = 0; j < 64; ++j) { float e_ = __expf(sd[tid][j] - m); sd[tid][j] = e_; sum += e_; }
        float inv = 1.f / sum;
        for (int j = 0; j < 64; ++j) sd[tid][j] *= inv;
    }
    __syncthreads();
    for (int e = tid; e < 4096; e += 256)
        wattn[(size_t)bh * 4096 + e] = sd[e >> 6][e & 63];
}

// ---------------- agg = attn @ gf, scatter to fmap (b,96,32,32) --------------
__global__ __launch_bounds__(256)
void attn2b(const float* __restrict__ wattn, const float* __restrict__ gf,
            float* __restrict__ fmap)
{
    int blk = blockIdx.x;
    int ct = blk & 3, bh = blk >> 2;
    int b = bh / 3, h = bh - b * 3;
    __shared__ float sa[64][65];
    __shared__ float sg[64][129];
    int tid = threadIdx.x;
    for (int e = tid; e < 4096; e += 256) sa[e >> 6][e & 63] = wattn[(size_t)bh * 4096 + e];
    for (int e = tid; e < 8192; e += 256) {
        int j = e >> 7, c = e & 127;
        sg[j][c] = gf[((size_t)bh * 64 + j) * 512 + ct * 128 + c];
    }
    __syncthreads();
    int txc = tid & 31, tyi = tid >> 5;
    float acc[8][4];
    #pragma unroll
    for (int ii = 0; ii < 8; ++ii)
        #pragma unroll
        for (int c = 0; c < 4; ++c) acc[ii][c] = 0.f;
    for (int j = 0; j < 64; ++j) {
        float g0[4];
        #pragma unroll
        for (int c = 0; c < 4; ++c) g0[c] = sg[j][txc + c * 32];
        #pragma unroll
        for (int ii = 0; ii < 8; ++ii) {
            float a = sa[tyi + ii * 8][j];
            #pragma unroll
            for (int c = 0; c < 4; ++c) acc[ii][c] += a * g0[c];
        }
    }
    __syncthreads();
    #pragma unroll
    for (int ii = 0; ii < 8; ++ii)
        #pragma unroll
        for (int c = 0; c < 4; ++c)
            sg[tyi + ii * 8][txc + c * 32] = acc[ii][c];
    __syncthreads();
    for (int e = tid; e < 8192; e += 256) {
        int d = e >> 8;
        int nx = (e >> 5) & 7;
        int cp = e & 31;
        int ny = cp >> 2, gy = cp & 3;
        float v = sg[nx * 8 + ny][gy * 32 + d];
        fmap[(((size_t)b * 96 + h * 32 + d) * 32 + nx * 4 + ct) * 32 + cp] = v;
    }
}

// -----------------------------------------------------------------------------
extern "C" void kernel_launch(void* const* d_in, const int* in_sizes, int n_in,
                              void* d_out, int out_size, void* d_ws, size_t ws_size,
                              hipStream_t stream)
{
    const float* x      = (const float*)d_in[0];
    const float* tok    = (const float*)d_in[1];
    const float* qkv_wb = (const float*)d_in[2];
    const float* qkv_ws = (const float*)d_in[3];
    const float* lng    = (const float*)d_in[4];
    const float* lnb    = (const float*)d_in[5];
    const float* gt_wb  = (const float*)d_in[6];
    const float* gt_ws  = (const float*)d_in[7];
    const float* out_wb = (const float*)d_in[8];
    const float* out_ws = (const float*)d_in[9];
    float* out = (float*)d_out;
    float* ws  = (float*)d_ws;

    const size_t OFF_QKV   = 0;            // 40,108,032 floats
    const size_t OFF_FMAP  = 0;            // reuses dead qkv region
    const size_t OFF_WATTN = 12582912;
    const size_t OFF_WC2   = 40108032;     // 165,888
    const size_t OFF_GT    = OFF_WC2 + 165888;
    const size_t OFF_GF    = OFF_GT + 786432;
    const size_t OFF_HH    = OFF_GF + 12582912;
    const size_t OFF_QK    = OFF_HH + 786432;
    const size_t OFF_WF1   = OFF_QK + 1572864;    // 995,328 B as 248,832 floats
    const size_t OFF_WF3   = OFF_WF1 + 248832;    // 331,776 B as 82,944 floats
    const size_t TOTAL     = OFF_WF3 + 82944;     // 56,334,336 floats
    if (ws_size < TOTAL * sizeof(float)) return;

    unsigned short* wf1 = (unsigned short*)(ws + OFF_WF1);
    unsigned short* wf3 = (unsigned short*)(ws + OFF_WF3);

    prep_w<<<648, 256, 0, stream>>>(gt_wb, gt_ws, ws + OFF_WC2, 192);
    prep_frag<<<(27 * 18 * 64 + 255) / 256, 256, 0, stream>>>(qkv_wb, qkv_ws, wf1, 18);
    prep_frag<<<(27 * 6 * 64 + 255) / 256, 256, 0, stream>>>(out_wb, out_ws, wf3, 6);

    kan_mfma<288, 0><<<1088, 512, 0, stream>>>(x, tok, wf1, ws + OFF_QKV);
    attn1<<<8192, 256, 0, stream>>>(ws + OFF_QKV, ws + OFF_GT, ws + OFF_GF);
    ln_gelu<<<3072, 256, 0, stream>>>(ws + OFF_GT, lng, lnb, ws + OFF_HH);
    kan_gemm<192, 64, 8192, false><<<dim3(64, 2), 256, 0, stream>>>(ws + OFF_HH, nullptr, ws + OFF_WC2, ws + OFF_QK);
    attn2a<<<384, 256, 0, stream>>>(ws + OFF_QK, ws + OFF_WATTN);
    attn2b<<<1536, 256, 0, stream>>>(ws + OFF_WATTN, ws + OFF_GF, ws + OFF_FMAP);
    kan_mfma<96, 1><<<1024, 512, 0, stream>>>(ws + OFF_FMAP, nullptr, wf3, out);
}

// Round 5
// 688.114 us; speedup vs baseline: 2.1286x; 1.0025x over previous
//
#include <hip/hip_runtime.h>
#include <cstddef>

#define SCALE 0.17677669529663687f
#define EPS 1e-5f

typedef __attribute__((ext_vector_type(8))) __bf16 bf16x8;
typedef __attribute__((ext_vector_type(4))) float f32x4;
typedef __attribute__((ext_vector_type(8))) unsigned short ushort8;

__device__ __forceinline__ unsigned short f2bf(float f) {
    unsigned u = __float_as_uint(f);
    return (unsigned short)((u + 0x7fffu + ((u >> 16) & 1u)) >> 16);
}
__device__ __forceinline__ float bf2f(unsigned short h) {
    return __uint_as_float(((unsigned)h) << 16);
}

#define GLD_LDS16(gsrc, ldst) \
    __builtin_amdgcn_global_load_lds((const __attribute__((address_space(1))) void*)(gsrc), \
                                     (__attribute__((address_space(3))) void*)(ldst), 16, 0, 0)

// ============ prep: pack W into MFMA A-fragments, split hi/lo bf16 ============
// K-order: step s = f*3+cg covers feature f=s/3, channels cg*32..+31.
// Frag layout per step: frag id = mt*2+h (h=0 hi, 1 lo), 1024B lane-linear:
// lane l slot holds W[m = mt*16+(l&15)][k-slot j], c = cg*32+(l>>4)*8+j.
__global__ __launch_bounds__(256)
void prep_frag(const float* __restrict__ wb, const float* __restrict__ ws,
               unsigned short* __restrict__ Wf, int MT16)
{
    int idx = blockIdx.x * 256 + threadIdx.x;
    int total = 27 * MT16 * 64;
    if (idx >= total) return;
    int lane = idx & 63;
    int t = idx >> 6;
    int mt = t % MT16;
    int s = t / MT16;
    int f = s / 3, cg = s - f * 3;
    int m = mt * 16 + (lane & 15);
    ushort8 hv, lv;
    #pragma unroll
    for (int j = 0; j < 8; ++j) {
        int c = cg * 32 + (lane >> 4) * 8 + j;
        float w = (f == 0) ? wb[m * 96 + c] : ws[(m * 96 + c) * 8 + (f - 1)];
        unsigned short hi = f2bf(w);
        unsigned short lo = f2bf(w - bf2f(hi));
        hv[j] = hi; lv[j] = lo;
    }
    size_t base = (size_t)((s * MT16 + mt) * 2) * 512 + lane * 8;
    *reinterpret_cast<ushort8*>(Wf + base) = hv;
    *reinterpret_cast<ushort8*>(Wf + base + 512) = lv;
}

// ---------------- phi generation: 8 values -> one hi frag slot + one lo ------
template<int CG>
__device__ __forceinline__ void phi_gen(const float (&xr)[24], int f,
                                        char* sBh, char* sBl, int lane)
{
    ushort8 hv, lv;
    float center = -2.f + (f - 1) * (4.f / 7.f);
    #pragma unroll
    for (int j = 0; j < 8; ++j) {
        float xv = xr[CG * 8 + j];
        float ph;
        if (f == 0) ph = xv / (1.f + __expf(-xv));
        else { float t = (xv - center) * 1.75f; ph = __expf(-t * t); }
        unsigned short hi = f2bf(ph);
        unsigned short lo = f2bf(ph - bf2f(hi));
        hv[j] = hi; lv[j] = lo;
    }
    *reinterpret_cast<ushort8*>(sBh + lane * 16) = hv;
    *reinterpret_cast<ushort8*>(sBl + lane * 16) = lv;
}

// MT = per-wave m-tiles (wave grid 2x4)
template<int MT>
__device__ __forceinline__ void mfma_step(const char* sAp, const char* sBp,
                                          f32x4 (&acc)[MT][2], int lane, int wm, int wn)
{
    bf16x8 bfr[2][2];
    #pragma unroll
    for (int nt = 0; nt < 2; ++nt)
        #pragma unroll
        for (int h = 0; h < 2; ++h)
            bfr[nt][h] = *reinterpret_cast<const bf16x8*>(
                sBp + (((wn * 2 + nt) * 2 + h) * 1024) + lane * 16);
    #pragma unroll
    for (int mt = 0; mt < MT; ++mt) {
        bf16x8 ah = *reinterpret_cast<const bf16x8*>(
            sAp + (((wm * MT + mt) * 2 + 0) * 1024) + lane * 16);
        bf16x8 al = *reinterpret_cast<const bf16x8*>(
            sAp + (((wm * MT + mt) * 2 + 1) * 1024) + lane * 16);
        #pragma unroll
        for (int nt = 0; nt < 2; ++nt) {
            acc[mt][nt] = __builtin_amdgcn_mfma_f32_16x16x32_bf16(ah, bfr[nt][0], acc[mt][nt], 0, 0, 0);
            acc[mt][nt] = __builtin_amdgcn_mfma_f32_16x16x32_bf16(ah, bfr[nt][1], acc[mt][nt], 0, 0, 0);
            acc[mt][nt] = __builtin_amdgcn_mfma_f32_16x16x32_bf16(al, bfr[nt][0], acc[mt][nt], 0, 0, 0);
        }
    }
}

// ============ fused-phi split-bf16 MFMA KAN GEMM =============================
// M_TOTAL rows total; each block computes a 96-row m-block (blockIdx.y) for a
// 128-col n-tile. LDS = 2*12KiB (A dbuf) + 2*16KiB (B dbuf) = 56 KiB -> 2 blk/CU.
// MODE 0: windowed gather (L1, out [M][139264]);  MODE 1: fmap (L3, out [b][M][1024])
template<int M_TOTAL, int MODE>
__global__ __launch_bounds__(512, 4)
void kan_mfma(const float* __restrict__ xin, const float* __restrict__ token,
              const unsigned short* __restrict__ Wf, float* __restrict__ out)
{
    constexpr int NFT = (M_TOTAL / 16) * 2;   // frags per step in Wf (all m)
    constexpr int NF = 12;                    // frags per step this block (96 rows)
    constexpr int MT = 3;                     // per-wave m-tiles (wave grid 2x4)
    __shared__ char sA[2 * NF * 1024];
    __shared__ char sB[2 * 16 * 1024];

    const int tid = threadIdx.x, lane = tid & 63, wid = tid >> 6;
    const int wm = wid >> 2, wn = wid & 3;
    const int n0 = blockIdx.x * 128;
    const int mb = blockIdx.y;                // m-block (96 rows)

    auto issueA = [&](int s, int buf) {
        for (int c = wid; c < NF; c += 8) {
            const unsigned short* src = Wf + (size_t)(s * NFT + mb * NF + c) * 512 + lane * 8;
            char* dst = sA + (buf * NF + c) * 1024;
            GLD_LDS16(src, dst);
        }
    };
    issueA(0, 0);

    // ---- gather the 24 x-values this thread contributes to phi -------------
    const int mycol = wid * 16 + (lane & 15);
    const int p = n0 + mycol;
    const float* gbase;
    int gstride;
    if (MODE == 0) {
        int w = p / 17, l = p - w * 17;
        if (l == 0) { gbase = token; gstride = 1; }
        else {
            int b = w >> 6, wl = w & 63;
            int wx = wl >> 3, wy = wl & 7;
            int jj = l - 1, gx = jj >> 2, gy = jj & 3;
            gbase = xin + (size_t)b * 98304 + (wx * 4 + gx) * 32 + wy * 4 + gy;
            gstride = 1024;
        }
    } else {
        gbase = xin + (size_t)(p >> 10) * 98304 + (p & 1023);
        gstride = 1024;
    }
    const int g8 = (lane >> 4) * 8;
    float xr[24];
    #pragma unroll
    for (int cg = 0; cg < 3; ++cg)
        #pragma unroll
        for (int j = 0; j < 8; ++j)
            xr[cg * 8 + j] = gbase[(size_t)(cg * 32 + g8 + j) * gstride];

    f32x4 acc[MT][2];
    #pragma unroll
    for (int mt = 0; mt < MT; ++mt)
        #pragma unroll
        for (int nt = 0; nt < 2; ++nt) {
            f32x4 z = {0.f, 0.f, 0.f, 0.f};
            acc[mt][nt] = z;
        }

    // phi for s=0 (f=0, cg=0) into sB buffer 0
    phi_gen<0>(xr, 0, sB + (wid * 2 + 0) * 1024, sB + (wid * 2 + 1) * 1024, lane);

#define STEP(CG) {                                                              \
        const int s_ = f * 3 + CG;                                              \
        const int sbuf_ = s_ & 1;                                               \
        __syncthreads();                                                        \
        if (s_ + 1 < 27) issueA(s_ + 1, (s_ + 1) & 1);                          \
        mfma_step<MT>(sA + sbuf_ * NF * 1024, sB + sbuf_ * 16 * 1024,           \
                      acc, lane, wm, wn);                                       \
        if (s_ + 1 < 27)                                                        \
            phi_gen<(CG + 1) % 3>(xr, (CG == 2) ? f + 1 : f,                    \
                sB + (((sbuf_ ^ 1) * 16 + wid * 2 + 0) * 1024),                 \
                sB + (((sbuf_ ^ 1) * 16 + wid * 2 + 1) * 1024), lane);          \
    }

    for (int f = 0; f < 9; ++f) { STEP(0) STEP(1) STEP(2) }
#undef STEP

    // ---- epilogue ----
    #pragma unroll
    for (int mt = 0; mt < MT; ++mt) {
        const int row = mb * 96 + wm * 48 + mt * 16 + (lane >> 4) * 4;
        #pragma unroll
        for (int nt = 0; nt < 2; ++nt) {
            const int col_l = wn * 32 + nt * 16 + (lane & 15);
            #pragma unroll
            for (int r = 0; r < 4; ++r) {
                float v = acc[mt][nt][r];
                if (MODE == 0)
                    out[(size_t)(row + r) * 139264 + n0 + col_l] = v;
                else {
                    int col = n0 + col_l;
                    out[(size_t)(col >> 10) * 98304 + (size_t)(row + r) * 1024 + (col & 1023)] = v;
                }
            }
        }
    }
}

// ---------------- weight prep for L2 (fp32 path): Wc[k][o], k=c*9+f ----------
__global__ __launch_bounds__(256)
void prep_w(const float* __restrict__ wb, const float* __restrict__ ws,
            float* __restrict__ Wc, int M)
{
    int idx = blockIdx.x * 256 + threadIdx.x;
    if (idx >= 864 * M) return;
    int k = idx / M, o = idx - k * M;
    int c = k / 9, f = k - c * 9;
    Wc[idx] = (f == 0) ? wb[o * 96 + c] : ws[(o * 96 + c) * 8 + (f - 1)];
}

// ---------------- fp32 fused-phi KAN GEMM (kept for L2) ----------------------
constexpr int BN_ = 128;
constexpr int BM_ = 96;
constexpr int CH_ = 4;
constexpr int BK_ = CH_ * 9;

template<int M, int LIN, int OUTL, bool WINDOWED>
__global__ __launch_bounds__(256)
void kan_gemm(const float* __restrict__ in, const float* __restrict__ token,
              const float* __restrict__ Wc, float* __restrict__ out)
{
    __shared__ float sW[BK_][BM_];
    __shared__ float sP[BK_][BN_];

    int tid = threadIdx.x;
    int n0 = blockIdx.x * BN_;
    int m0 = blockIdx.y * BM_;

    int col = tid & 127;
    int p = n0 + col;
    const float* myPtr;
    int myStride;
    if (WINDOWED) {
        int w = p / 17, l = p - w * 17;
        if (l == 0) { myPtr = token; myStride = 1; }
        else {
            int b = w >> 6, wl = w & 63;
            int wx = wl >> 3, wy = wl & 7;
            int j = l - 1, gx = j >> 2, gy = j & 3;
            myPtr = in + (size_t)b * 98304 + (wx * 4 + gx) * 32 + wy * 4 + gy;
            myStride = 1024;
        }
    } else {
        int nb = p / LIN, l = p - nb * LIN;
        myPtr = in + (size_t)nb * (96 * LIN) + l;
        myStride = LIN;
    }

    int tx = tid & 15, ty = tid >> 4;
    float acc[6][8] = {};

    for (int ch = 0; ch < 96; ch += CH_) {
        __syncthreads();
        for (int idx = tid; idx < BK_ * BM_ / 4; idx += 256) {
            int kk = idx / (BM_ / 4), mm = idx - kk * (BM_ / 4);
            reinterpret_cast<float4*>(sW[kk])[mm] =
                reinterpret_cast<const float4*>(Wc + (size_t)(ch * 9 + kk) * M + m0)[mm];
        }
        #pragma unroll
        for (int it = 0; it < 2; ++it) {
            int cc = (tid + it * 256) >> 7;
            float x = myPtr[(ch + cc) * myStride];
            float s = x / (1.f + __expf(-x));
            sP[cc * 9][col] = s;
            #pragma unroll
            for (int g = 0; g < 8; ++g) {
                float t = (x - (-2.f + g * (4.f / 7.f))) * 1.75f;
                sP[cc * 9 + 1 + g][col] = __expf(-t * t);
            }
        }
        __syncthreads();
        #pragma unroll 6
        for (int k = 0; k < BK_; ++k) {
            float a[6], bb[8];
            #pragma unroll
            for (int j = 0; j < 6; ++j) a[j] = sW[k][ty + j * 16];
            #pragma unroll
            for (int i = 0; i < 8; ++i) bb[i] = sP[k][tx + i * 16];
            #pragma unroll
            for (int j = 0; j < 6; ++j)
                #pragma unroll
                for (int i = 0; i < 8; ++i)
                    acc[j][i] += a[j] * bb[i];
        }
    }

    size_t outBase = (size_t)(n0 / OUTL) * ((size_t)M * OUTL) + (size_t)(n0 % OUTL);
    #pragma unroll
    for (int j = 0; j < 6; ++j) {
        size_t rowOff = outBase + (size_t)(m0 + ty + j * 16) * OUTL + tx;
        #pragma unroll
        for (int i = 0; i < 8; ++i)
            out[rowOff + i * 16] = acc[j][i];
    }
}

// ---------------- window feature-attention (32x32, contract 17 tokens) -------
__global__ __launch_bounds__(256)
void attn1(const float* __restrict__ qkv, float* __restrict__ gt, float* __restrict__ gf)
{
    int w = blockIdx.x;
    int tid = threadIdx.x;
    __shared__ float sq[3][32][17];
    __shared__ float sk[3][32][17];
    __shared__ float sv[3][32][17];
    __shared__ float sa[3][32][33];
    const size_t N = 139264;

    for (int e = tid; e < 288 * 17; e += 256) {
        int row = e / 17, l = e - row * 17;
        float v = qkv[(size_t)row * N + (size_t)w * 17 + l];
        int sec = row / 96, ch = row - sec * 96;
        int h = ch >> 5, d = ch & 31;
        if (sec == 0)      sq[h][d][l] = v * SCALE;
        else if (sec == 1) sk[h][d][l] = v;
        else               sv[h][d][l] = v;
    }
    __syncthreads();
    for (int e = tid; e < 3 * 32 * 32; e += 256) {
        int h = e >> 10, r = e & 1023, i = r >> 5, j = r & 31;
        float s = 0.f;
        #pragma unroll
        for (int l = 0; l < 17; ++l) s += sq[h][i][l] * sk[h][j][l];
        sa[h][i][j] = s;
    }
    __syncthreads();
    if (tid < 96) {
        int h = tid >> 5, i = tid & 31;
        float m = -1e30f;
        for (int j = 0; j < 32; ++j) m = fmaxf(m, sa[h][i][j]);
        float sum = 0.f;
        for (int j = 0; j < 32; ++j) { float e_ = __expf(sa[h][i][j] - m); sa[h][i][j] = e_; sum += e_; }
        float inv = 1.f / sum;
        for (int j = 0; j < 32; ++j) sa[h][i][j] *= inv;
    }
    __syncthreads();
    int b = w >> 6, wl = w & 63;
    for (int e = tid; e < 3 * 17 * 32; e += 256) {
        int h = e / 544, r = e - h * 544, l = r >> 5, i = r & 31;
        float s = 0.f;
        #pragma unroll
        for (int j = 0; j < 32; ++j) s += sa[h][i][j] * sv[h][j][l];
        if (l == 0) gt[(((size_t)b * 3 + h) * 64 + wl) * 32 + i] = s;
        else        gf[((((size_t)b * 3 + h) * 64 + wl) * 16 + (l - 1)) * 32 + i] = s;
    }
}

// ---------------- LN (over 32) + exact GELU -> hh (b, 96, 64) ----------------
__global__ __launch_bounds__(256)
void ln_gelu(const float* __restrict__ gt, const float* __restrict__ lng,
             const float* __restrict__ lnb, float* __restrict__ hh)
{
    int row = blockIdx.x * 8 + (threadIdx.x >> 5);
    int d = threadIdx.x & 31;
    float x = gt[(size_t)row * 32 + d];
    float s = x, s2 = x * x;
    #pragma unroll
    for (int m = 16; m >= 1; m >>= 1) { s += __shfl_xor(s, m, 32); s2 += __shfl_xor(s2, m, 32); }
    float mu = s * (1.f / 32.f);
    float var = s2 * (1.f / 32.f) - mu * mu;
    float h = (x - mu) * rsqrtf(var + EPS) * lng[d] + lnb[d];
    float g = 0.5f * h * (1.f + erff(h * 0.70710678118654752f));
    int b = row / 192, r = row - b * 192;
    int hd = r >> 6, wl = r & 63;
    hh[((size_t)b * 96 + hd * 32 + d) * 64 + wl] = g;
}

// ---------------- window-token attention: dots + softmax ---------------------
__global__ __launch_bounds__(256)
void attn2a(const float* __restrict__ qk, float* __restrict__ wattn)
{
    int bh = blockIdx.x;
    int b = bh / 3, h = bh - b * 3;
    __shared__ float swq[64][33];
    __shared__ float swk[64][33];
    __shared__ float sd[64][65];
    int tid = threadIdx.x;
    for (int e = tid; e < 2048; e += 256) {
        int d = e >> 6, i = e & 63;
        swq[i][d] = qk[((size_t)h * 64 + d) * 8192 + b * 64 + i] * SCALE;
        swk[i][d] = qk[((size_t)h * 64 + 32 + d) * 8192 + b * 64 + i];
    }
    __syncthreads();
    for (int e = tid; e < 4096; e += 256) {
        int i = e >> 6, j = e & 63;
        float s = 0.f;
        #pragma unroll
        for (int d = 0; d < 32; ++d) s += swq[i][d] * swk[j][d];
        sd[i][j] = s;
    }
    __syncthreads();
    if (tid < 64) {
        float m = -1e30f;
        for (int j = 0; j < 64; ++j) m = fmaxf(m, sd[tid][j]);
        float sum = 0.f;
        for (int j = 0; j < 64; ++j) { float e_ = __expf(sd[tid][j] - m); sd[tid][j] = e_; sum += e_; }
        float inv = 1.f / sum;
        for (int j = 0; j < 64; ++j) sd[tid][j] *= inv;
    }
    __syncthreads();
    for (int e = tid; e < 4096; e += 256)
        wattn[(size_t)bh * 4096 + e] = sd[e >> 6][e & 63];
}

// ---------------- agg = attn @ gf, scatter to fmap (b,96,32,32) --------------
__global__ __launch_bounds__(256)
void attn2b(const float* __restrict__ wattn, const float* __restrict__ gf,
            float* __restrict__ fmap)
{
    int blk = blockIdx.x;
    int ct = blk & 3, bh = blk >> 2;
    int b = bh / 3, h = bh - b * 3;
    __shared__ float sa[64][65];
    __shared__ float sg[64][129];
    int tid = threadIdx.x;
    for (int e = tid; e < 4096; e += 256) sa[e >> 6][e & 63] = wattn[(size_t)bh * 4096 + e];
    for (int e = tid; e < 8192; e += 256) {
        int j = e >> 7, c = e & 127;
        sg[j][c] = gf[((size_t)bh * 64 + j) * 512 + ct * 128 + c];
    }
    __syncthreads();
    int txc = tid & 31, tyi = tid >> 5;
    float acc[8][4];
    #pragma unroll
    for (int ii = 0; ii < 8; ++ii)
        #pragma unroll
        for (int c = 0; c < 4; ++c) acc[ii][c] = 0.f;
    for (int j = 0; j < 64; ++j) {
        float g0[4];
        #pragma unroll
        for (int c = 0; c < 4; ++c) g0[c] = sg[j][txc + c * 32];
        #pragma unroll
        for (int ii = 0; ii < 8; ++ii) {
            float a = sa[tyi + ii * 8][j];
            #pragma unroll
            for (int c = 0; c < 4; ++c) acc[ii][c] += a * g0[c];
        }
    }
    __syncthreads();
    #pragma unroll
    for (int ii = 0; ii < 8; ++ii)
        #pragma unroll
        for (int c = 0; c < 4; ++c)
            sg[tyi + ii * 8][txc + c * 32] = acc[ii][c];
    __syncthreads();
    for (int e = tid; e < 8192; e += 256) {
        int d = e >> 8;
        int nx = (e >> 5) & 7;
        int cp = e & 31;
        int ny = cp >> 2, gy = cp & 3;
        float v = sg[nx * 8 + ny][gy * 32 + d];
        fmap[(((size_t)b * 96 + h * 32 + d) * 32 + nx * 4 + ct) * 32 + cp] = v;
    }
}

// -----------------------------------------------------------------------------
extern "C" void kernel_launch(void* const* d_in, const int* in_sizes, int n_in,
                              void* d_out, int out_size, void* d_ws, size_t ws_size,
                              hipStream_t stream)
{
    const float* x      = (const float*)d_in[0];
    const float* tok    = (const float*)d_in[1];
    const float* qkv_wb = (const float*)d_in[2];
    const float* qkv_ws = (const float*)d_in[3];
    const float* lng    = (const float*)d_in[4];
    const float* lnb    = (const float*)d_in[5];
    const float* gt_wb  = (const float*)d_in[6];
    const float* gt_ws  = (const float*)d_in[7];
    const float* out_wb = (const float*)d_in[8];
    const float* out_ws = (const float*)d_in[9];
    float* out = (float*)d_out;
    float* ws  = (float*)d_ws;

    const size_t OFF_QKV   = 0;            // 40,108,032 floats
    const size_t OFF_FMAP  = 0;            // reuses dead qkv region
    const size_t OFF_WATTN = 12582912;
    const size_t OFF_WC2   = 40108032;     // 165,888
    const size_t OFF_GT    = OFF_WC2 + 165888;
    const size_t OFF_GF    = OFF_GT + 786432;
    const size_t OFF_HH    = OFF_GF + 12582912;
    const size_t OFF_QK    = OFF_HH + 786432;
    const size_t OFF_WF1   = OFF_QK + 1572864;    // 995,328 B as 248,832 floats
    const size_t OFF_WF3   = OFF_WF1 + 248832;    // 331,776 B as 82,944 floats
    const size_t TOTAL     = OFF_WF3 + 82944;     // 56,334,336 floats
    if (ws_size < TOTAL * sizeof(float)) return;

    unsigned short* wf1 = (unsigned short*)(ws + OFF_WF1);
    unsigned short* wf3 = (unsigned short*)(ws + OFF_WF3);

    prep_w<<<648, 256, 0, stream>>>(gt_wb, gt_ws, ws + OFF_WC2, 192);
    prep_frag<<<(27 * 18 * 64 + 255) / 256, 256, 0, stream>>>(qkv_wb, qkv_ws, wf1, 18);
    prep_frag<<<(27 * 6 * 64 + 255) / 256, 256, 0, stream>>>(out_wb, out_ws, wf3, 6);

    kan_mfma<288, 0><<<dim3(1088, 3), 512, 0, stream>>>(x, tok, wf1, ws + OFF_QKV);
    attn1<<<8192, 256, 0, stream>>>(ws + OFF_QKV, ws + OFF_GT, ws + OFF_GF);
    ln_gelu<<<3072, 256, 0, stream>>>(ws + OFF_GT, lng, lnb, ws + OFF_HH);
    kan_gemm<192, 64, 8192, false><<<dim3(64, 2), 256, 0, stream>>>(ws + OFF_HH, nullptr, ws + OFF_WC2, ws + OFF_QK);
    attn2a<<<384, 256, 0, stream>>>(ws + OFF_QK, ws + OFF_WATTN);
    attn2b<<<1536, 256, 0, stream>>>(ws + OFF_WATTN, ws + OFF_GF, ws + OFF_FMAP);
    kan_mfma<96, 1><<<dim3(1024, 1), 512, 0, stream>>>(ws + OFF_FMAP, nullptr, wf3, out);
}

// Round 6
// 646.639 us; speedup vs baseline: 2.2652x; 1.0641x over previous
//
#include <hip/hip_runtime.h>
#include <cstddef>

#define SCALE 0.17677669529663687f
#define EPS 1e-5f

typedef __attribute__((ext_vector_type(8))) __bf16 bf16x8;
typedef __attribute__((ext_vector_type(4))) float f32x4;
typedef __attribute__((ext_vector_type(8))) unsigned short ushort8;

__device__ __forceinline__ unsigned short f2bf(float f) {
    unsigned u = __float_as_uint(f);
    return (unsigned short)((u + 0x7fffu + ((u >> 16) & 1u)) >> 16);
}
__device__ __forceinline__ float bf2f(unsigned short h) {
    return __uint_as_float(((unsigned)h) << 16);
}
__device__ __forceinline__ unsigned cvt_pk_bf16(float a, float b) {
    unsigned r;
    asm("v_cvt_pk_bf16_f32 %0, %1, %2" : "=v"(r) : "v"(a), "v"(b));
    return r;
}

#define GLD_LDS16(gsrc, ldst) \
    __builtin_amdgcn_global_load_lds((const __attribute__((address_space(1))) void*)(gsrc), \
                                     (__attribute__((address_space(3))) void*)(ldst), 16, 0, 0)

// ============ prep: pack W into MFMA A-fragments, split hi/lo bf16 ============
// K-order: step s = f*3+cg covers feature f=s/3, channels cg*32..+31.
// Frag id per step = mt*2+h (h=0 hi, 1 lo), 1024B lane-linear:
// lane l holds W[m = mt*16+(l&15)], c = cg*32+(l>>4)*8+j  (j=0..7).
__global__ __launch_bounds__(256)
void prep_frag(const float* __restrict__ wb, const float* __restrict__ ws,
               unsigned short* __restrict__ Wf, int MT16)
{
    int idx = blockIdx.x * 256 + threadIdx.x;
    int total = 27 * MT16 * 64;
    if (idx >= total) return;
    int lane = idx & 63;
    int t = idx >> 6;
    int mt = t % MT16;
    int s = t / MT16;
    int f = s / 3, cg = s - f * 3;
    int m = mt * 16 + (lane & 15);
    ushort8 hv, lv;
    #pragma unroll
    for (int j = 0; j < 8; ++j) {
        int c = cg * 32 + (lane >> 4) * 8 + j;
        float w = (f == 0) ? wb[m * 96 + c] : ws[(m * 96 + c) * 8 + (f - 1)];
        unsigned short hi = f2bf(w);
        unsigned short lo = f2bf(w - bf2f(hi));
        hv[j] = hi; lv[j] = lo;
    }
    size_t base = (size_t)((s * MT16 + mt) * 2) * 512 + lane * 8;
    *reinterpret_cast<ushort8*>(Wf + base) = hv;
    *reinterpret_cast<ushort8*>(Wf + base + 512) = lv;
}

// ---------------- phi: 8 values -> one bf16 B-frag slot (rounded) ------------
template<int CG>
__device__ __forceinline__ void phi_gen2(const float (&xr)[24], int f,
                                         char* dst, int lane)
{
    float ph[8];
    if (f == 0) {
        #pragma unroll
        for (int j = 0; j < 8; ++j) {
            float xv = xr[CG * 8 + j];
            ph[j] = xv / (1.f + __expf(-xv));
        }
    } else {
        const float bias = 3.5f - (float)(f - 1);
        #pragma unroll
        for (int j = 0; j < 8; ++j) {
            float t = fmaf(xr[CG * 8 + j], 1.75f, bias);
            ph[j] = __expf(-(t * t));
        }
    }
    uint4 w;
    w.x = cvt_pk_bf16(ph[0], ph[1]);
    w.y = cvt_pk_bf16(ph[2], ph[3]);
    w.z = cvt_pk_bf16(ph[4], ph[5]);
    w.w = cvt_pk_bf16(ph[6], ph[7]);
    *reinterpret_cast<uint4*>(dst + lane * 16) = w;
}

// 2 MFMA per (mt,nt): acc += Whi*phi + Wlo*phi
template<int MT>
__device__ __forceinline__ void mfma_step2(const char* sAp, const char* sBp,
                                           f32x4 (&acc)[MT][2], int lane, int wm, int wn)
{
    bf16x8 bfr[2];
    #pragma unroll
    for (int nt = 0; nt < 2; ++nt)
        bfr[nt] = *reinterpret_cast<const bf16x8*>(sBp + (wn * 2 + nt) * 1024 + lane * 16);
    #pragma unroll
    for (int mt = 0; mt < MT; ++mt) {
        bf16x8 ah = *reinterpret_cast<const bf16x8*>(
            sAp + (((wm * MT + mt) * 2 + 0) * 1024) + lane * 16);
        bf16x8 al = *reinterpret_cast<const bf16x8*>(
            sAp + (((wm * MT + mt) * 2 + 1) * 1024) + lane * 16);
        #pragma unroll
        for (int nt = 0; nt < 2; ++nt) {
            acc[mt][nt] = __builtin_amdgcn_mfma_f32_16x16x32_bf16(ah, bfr[nt], acc[mt][nt], 0, 0, 0);
            acc[mt][nt] = __builtin_amdgcn_mfma_f32_16x16x32_bf16(al, bfr[nt], acc[mt][nt], 0, 0, 0);
        }
    }
}

// ============ fused-phi split-W MFMA KAN GEMM ================================
// Each block: 96 output rows (blockIdx.y m-block) x 128 cols (blockIdx.x).
// LDS: A dbuf 2*12KiB + B dbuf 2*8KiB = 40 KiB.
// MODE 0: windowed gather (L1, out [M][139264])
// MODE 1: fmap gather    (L3, out [b][M][1024])
// MODE 2: lin64 gather   (L2, out [M][8192])
template<int M_TOTAL, int MODE>
__global__ __launch_bounds__(512, 6)
void kan_mfma(const float* __restrict__ xin, const float* __restrict__ token,
              const unsigned short* __restrict__ Wf, float* __restrict__ out)
{
    constexpr int NFT = (M_TOTAL / 16) * 2;   // A frags per step in Wf (all m)
    constexpr int NF = 12;                    // A frags per step this block
    constexpr int MT = 3;                     // per-wave m-tiles (wave grid 2x4)
    __shared__ char sA[2 * NF * 1024];
    __shared__ char sB[2 * 8 * 1024];

    const int tid = threadIdx.x, lane = tid & 63, wid = tid >> 6;
    const int wm = wid >> 2, wn = wid & 3;
    const int n0 = blockIdx.x * 128;
    const int mb = blockIdx.y;                // m-block (96 rows)

    auto issueA = [&](int s, int buf) {
        for (int c = wid; c < NF; c += 8) {
            const unsigned short* src = Wf + (size_t)(s * NFT + mb * NF + c) * 512 + lane * 8;
            char* dst = sA + (buf * NF + c) * 1024;
            GLD_LDS16(src, dst);
        }
    };
    issueA(0, 0);

    // ---- gather the 24 x-values this thread contributes to phi -------------
    const int mycol = wid * 16 + (lane & 15);
    const int p = n0 + mycol;
    const float* gbase;
    int gstride;
    if (MODE == 0) {
        int w = p / 17, l = p - w * 17;
        if (l == 0) { gbase = token; gstride = 1; }
        else {
            int b = w >> 6, wl = w & 63;
            int wx = wl >> 3, wy = wl & 7;
            int jj = l - 1, gx = jj >> 2, gy = jj & 3;
            gbase = xin + (size_t)b * 98304 + (wx * 4 + gx) * 32 + wy * 4 + gy;
            gstride = 1024;
        }
    } else if (MODE == 1) {
        gbase = xin + (size_t)(p >> 10) * 98304 + (p & 1023);
        gstride = 1024;
    } else {
        gbase = xin + (size_t)(p >> 6) * 6144 + (p & 63);
        gstride = 64;
    }
    const int g8 = (lane >> 4) * 8;
    float xr[24];
    #pragma unroll
    for (int cg = 0; cg < 3; ++cg)
        #pragma unroll
        for (int j = 0; j < 8; ++j)
            xr[cg * 8 + j] = gbase[(size_t)(cg * 32 + g8 + j) * gstride];

    f32x4 acc[MT][2];
    #pragma unroll
    for (int mt = 0; mt < MT; ++mt)
        #pragma unroll
        for (int nt = 0; nt < 2; ++nt) {
            f32x4 z = {0.f, 0.f, 0.f, 0.f};
            acc[mt][nt] = z;
        }

    // phi for s=0 (f=0, cg=0) into sB buffer 0 (frag wid holds cols wid*16..+15)
    phi_gen2<0>(xr, 0, sB + wid * 1024, lane);

#define STEP(CG) {                                                              \
        const int s_ = f * 3 + CG;                                              \
        const int sbuf_ = s_ & 1;                                               \
        __syncthreads();                                                        \
        if (s_ + 1 < 27) issueA(s_ + 1, (s_ + 1) & 1);                          \
        mfma_step2<MT>(sA + sbuf_ * NF * 1024, sB + sbuf_ * 8 * 1024,           \
                       acc, lane, wm, wn);                                      \
        if (s_ + 1 < 27)                                                        \
            phi_gen2<(CG + 1) % 3>(xr, (CG == 2) ? f + 1 : f,                   \
                sB + ((sbuf_ ^ 1) * 8 + wid) * 1024, lane);                     \
    }

    for (int f = 0; f < 9; ++f) { STEP(0) STEP(1) STEP(2) }
#undef STEP

    // ---- epilogue ----
    #pragma unroll
    for (int mt = 0; mt < MT; ++mt) {
        const int row = mb * 96 + wm * 48 + mt * 16 + (lane >> 4) * 4;
        #pragma unroll
        for (int nt = 0; nt < 2; ++nt) {
            const int col_l = wn * 32 + nt * 16 + (lane & 15);
            #pragma unroll
            for (int r = 0; r < 4; ++r) {
                float v = acc[mt][nt][r];
                if (MODE == 0)
                    out[(size_t)(row + r) * 139264 + n0 + col_l] = v;
                else if (MODE == 1) {
                    int col = n0 + col_l;
                    out[(size_t)(col >> 10) * 98304 + (size_t)(row + r) * 1024 + (col & 1023)] = v;
                } else {
                    out[(size_t)(row + r) * 8192 + n0 + col_l] = v;
                }
            }
        }
    }
}

// ---------------- window feature-attention (32x32, contract 17 tokens) -------
__global__ __launch_bounds__(256)
void attn1(const float* __restrict__ qkv, float* __restrict__ gt, float* __restrict__ gf)
{
    int w = blockIdx.x;
    int tid = threadIdx.x;
    __shared__ float sq[3][32][17];
    __shared__ float sk[3][32][17];
    __shared__ float sv[3][32][17];
    __shared__ float sa[3][32][33];
    const size_t N = 139264;

    for (int e = tid; e < 288 * 17; e += 256) {
        int row = e / 17, l = e - row * 17;
        float v = qkv[(size_t)row * N + (size_t)w * 17 + l];
        int sec = row / 96, ch = row - sec * 96;
        int h = ch >> 5, d = ch & 31;
        if (sec == 0)      sq[h][d][l] = v * SCALE;
        else if (sec == 1) sk[h][d][l] = v;
        else               sv[h][d][l] = v;
    }
    __syncthreads();
    for (int e = tid; e < 3 * 32 * 32; e += 256) {
        int h = e >> 10, r = e & 1023, i = r >> 5, j = r & 31;
        float s = 0.f;
        #pragma unroll
        for (int l = 0; l < 17; ++l) s += sq[h][i][l] * sk[h][j][l];
        sa[h][i][j] = s;
    }
    __syncthreads();
    if (tid < 96) {
        int h = tid >> 5, i = tid & 31;
        float m = -1e30f;
        for (int j = 0; j < 32; ++j) m = fmaxf(m, sa[h][i][j]);
        float sum = 0.f;
        for (int j = 0; j < 32; ++j) { float e_ = __expf(sa[h][i][j] - m); sa[h][i][j] = e_; sum += e_; }
        float inv = 1.f / sum;
        for (int j = 0; j < 32; ++j) sa[h][i][j] *= inv;
    }
    __syncthreads();
    int b = w >> 6, wl = w & 63;
    for (int e = tid; e < 3 * 17 * 32; e += 256) {
        int h = e / 544, r = e - h * 544, l = r >> 5, i = r & 31;
        float s = 0.f;
        #pragma unroll
        for (int j = 0; j < 32; ++j) s += sa[h][i][j] * sv[h][j][l];
        if (l == 0) gt[(((size_t)b * 3 + h) * 64 + wl) * 32 + i] = s;
        else        gf[((((size_t)b * 3 + h) * 64 + wl) * 16 + (l - 1)) * 32 + i] = s;
    }
}

// ---------------- LN (over 32) + exact GELU -> hh (b, 96, 64) ----------------
__global__ __launch_bounds__(256)
void ln_gelu(const float* __restrict__ gt, const float* __restrict__ lng,
             const float* __restrict__ lnb, float* __restrict__ hh)
{
    int row = blockIdx.x * 8 + (threadIdx.x >> 5);
    int d = threadIdx.x & 31;
    float x = gt[(size_t)row * 32 + d];
    float s = x, s2 = x * x;
    #pragma unroll
    for (int m = 16; m >= 1; m >>= 1) { s += __shfl_xor(s, m, 32); s2 += __shfl_xor(s2, m, 32); }
    float mu = s * (1.f / 32.f);
    float var = s2 * (1.f / 32.f) - mu * mu;
    float h = (x - mu) * rsqrtf(var + EPS) * lng[d] + lnb[d];
    float g = 0.5f * h * (1.f + erff(h * 0.70710678118654752f));
    int b = row / 192, r = row - b * 192;
    int hd = r >> 6, wl = r & 63;
    hh[((size_t)b * 96 + hd * 32 + d) * 64 + wl] = g;
}

// ---------------- window-token attention: dots + softmax ---------------------
__global__ __launch_bounds__(256)
void attn2a(const float* __restrict__ qk, float* __restrict__ wattn)
{
    int bh = blockIdx.x;
    int b = bh / 3, h = bh - b * 3;
    __shared__ float swq[64][33];
    __shared__ float swk[64][33];
    __shared__ float sd[64][65];
    int tid = threadIdx.x;
    for (int e = tid; e < 2048; e += 256) {
        int d = e >> 6, i = e & 63;
        swq[i][d] = qk[((size_t)h * 64 + d) * 8192 + b * 64 + i] * SCALE;
        swk[i][d] = qk[((size_t)h * 64 + 32 + d) * 8192 + b * 64 + i];
    }
    __syncthreads();
    for (int e = tid; e < 4096; e += 256) {
        int i = e >> 6, j = e & 63;
        float s = 0.f;
        #pragma unroll
        for (int d = 0; d < 32; ++d) s += swq[i][d] * swk[j][d];
        sd[i][j] = s;
    }
    __syncthreads();
    if (tid < 64) {
        float m = -1e30f;
        for (int j = 0; j < 64; ++j) m = fmaxf(m, sd[tid][j]);
        float sum = 0.f;
        for (int j = 0; j < 64; ++j) { float e_ = __expf(sd[tid][j] - m); sd[tid][j] = e_; sum += e_; }
        float inv = 1.f / sum;
        for (int j = 0; j < 64; ++j) sd[tid][j] *= inv;
    }
    __syncthreads();
    for (int e = tid; e < 4096; e += 256)
        wattn[(size_t)bh * 4096 + e] = sd[e >> 6][e & 63];
}

// ---------------- agg = attn @ gf, scatter to fmap (b,96,32,32) --------------
__global__ __launch_bounds__(256)
void attn2b(const float* __restrict__ wattn, const float* __restrict__ gf,
            float* __restrict__ fmap)
{
    int blk = blockIdx.x;
    int ct = blk & 3, bh = blk >> 2;
    int b = bh / 3, h = bh - b * 3;
    __shared__ float sa[64][65];
    __shared__ float sg[64][129];
    int tid = threadIdx.x;
    for (int e = tid; e < 4096; e += 256) sa[e >> 6][e & 63] = wattn[(size_t)bh * 4096 + e];
    for (int e = tid; e < 8192; e += 256) {
        int j = e >> 7, c = e & 127;
        sg[j][c] = gf[((size_t)bh * 64 + j) * 512 + ct * 128 + c];
    }
    __syncthreads();
    int txc = tid & 31, tyi = tid >> 5;
    float acc[8][4];
    #pragma unroll
    for (int ii = 0; ii < 8; ++ii)
        #pragma unroll
        for (int c = 0; c < 4; ++c) acc[ii][c] = 0.f;
    for (int j = 0; j < 64; ++j) {
        float g0[4];
        #pragma unroll
        for (int c = 0; c < 4; ++c) g0[c] = sg[j][txc + c * 32];
        #pragma unroll
        for (int ii = 0; ii < 8; ++ii) {
            float a = sa[tyi + ii * 8][j];
            #pragma unroll
            for (int c = 0; c < 4; ++c) acc[ii][c] += a * g0[c];
        }
    }
    __syncthreads();
    #pragma unroll
    for (int ii = 0; ii < 8; ++ii)
        #pragma unroll
        for (int c = 0; c < 4; ++c)
            sg[tyi + ii * 8][txc + c * 32] = acc[ii][c];
    __syncthreads();
    for (int e = tid; e < 8192; e += 256) {
        int d = e >> 8;
        int nx = (e >> 5) & 7;
        int cp = e & 31;
        int ny = cp >> 2, gy = cp & 3;
        float v = sg[nx * 8 + ny][gy * 32 + d];
        fmap[(((size_t)b * 96 + h * 32 + d) * 32 + nx * 4 + ct) * 32 + cp] = v;
    }
}

// -----------------------------------------------------------------------------
extern "C" void kernel_launch(void* const* d_in, const int* in_sizes, int n_in,
                              void* d_out, int out_size, void* d_ws, size_t ws_size,
                              hipStream_t stream)
{
    const float* x      = (const float*)d_in[0];
    const float* tok    = (const float*)d_in[1];
    const float* qkv_wb = (const float*)d_in[2];
    const float* qkv_ws = (const float*)d_in[3];
    const float* lng    = (const float*)d_in[4];
    const float* lnb    = (const float*)d_in[5];
    const float* gt_wb  = (const float*)d_in[6];
    const float* gt_ws  = (const float*)d_in[7];
    const float* out_wb = (const float*)d_in[8];
    const float* out_ws = (const float*)d_in[9];
    float* out = (float*)d_out;
    float* ws  = (float*)d_ws;

    const size_t OFF_QKV   = 0;            // 40,108,032 floats
    const size_t OFF_FMAP  = 0;            // reuses dead qkv region
    const size_t OFF_WATTN = 12582912;
    const size_t OFF_WF2   = 40108032;     // 165,888 floats (27*24*512 shorts)
    const size_t OFF_GT    = OFF_WF2 + 165888;
    const size_t OFF_GF    = OFF_GT + 786432;
    const size_t OFF_HH    = OFF_GF + 12582912;
    const size_t OFF_QK    = OFF_HH + 786432;
    const size_t OFF_WF1   = OFF_QK + 1572864;    // 248,832 floats
    const size_t OFF_WF3   = OFF_WF1 + 248832;    // 82,944 floats
    const size_t TOTAL     = OFF_WF3 + 82944;     // 56,334,336 floats
    if (ws_size < TOTAL * sizeof(float)) return;

    unsigned short* wf1 = (unsigned short*)(ws + OFF_WF1);
    unsigned short* wf2 = (unsigned short*)(ws + OFF_WF2);
    unsigned short* wf3 = (unsigned short*)(ws + OFF_WF3);

    prep_frag<<<(27 * 18 * 64 + 255) / 256, 256, 0, stream>>>(qkv_wb, qkv_ws, wf1, 18);
    prep_frag<<<(27 * 12 * 64 + 255) / 256, 256, 0, stream>>>(gt_wb,  gt_ws,  wf2, 12);
    prep_frag<<<(27 * 6 * 64 + 255) / 256, 256, 0, stream>>>(out_wb, out_ws, wf3, 6);

    kan_mfma<288, 0><<<dim3(1088, 3), 512, 0, stream>>>(x, tok, wf1, ws + OFF_QKV);
    attn1<<<8192, 256, 0, stream>>>(ws + OFF_QKV, ws + OFF_GT, ws + OFF_GF);
    ln_gelu<<<3072, 256, 0, stream>>>(ws + OFF_GT, lng, lnb, ws + OFF_HH);
    kan_mfma<192, 2><<<dim3(64, 2), 512, 0, stream>>>(ws + OFF_HH, nullptr, wf2, ws + OFF_QK);
    attn2a<<<384, 256, 0, stream>>>(ws + OFF_QK, ws + OFF_WATTN);
    attn2b<<<1536, 256, 0, stream>>>(ws + OFF_WATTN, ws + OFF_GF, ws + OFF_FMAP);
    kan_mfma<96, 1><<<dim3(1024, 1), 512, 0, stream>>>(ws + OFF_FMAP, nullptr, wf3, out);
}

// Round 7
// 460.727 us; speedup vs baseline: 3.1792x; 1.4035x over previous
//
#include <hip/hip_runtime.h>
#include <cstddef>

#define SCALE 0.17677669529663687f
#define EPS 1e-5f

typedef __attribute__((ext_vector_type(8))) __bf16 bf16x8;
typedef __attribute__((ext_vector_type(4))) float f32x4;
typedef __attribute__((ext_vector_type(8))) unsigned short ushort8;

__device__ __forceinline__ unsigned short f2bf(float f) {
    unsigned u = __float_as_uint(f);
    return (unsigned short)((u + 0x7fffu + ((u >> 16) & 1u)) >> 16);
}
__device__ __forceinline__ float bf2f(unsigned short h) {
    return __uint_as_float(((unsigned)h) << 16);
}
__device__ __forceinline__ unsigned cvt_pk_bf16(float a, float b) {
    unsigned r;
    asm("v_cvt_pk_bf16_f32 %0, %1, %2" : "=v"(r) : "v"(a), "v"(b));
    return r;
}

#define GLD_LDS16(gsrc, ldst) \
    __builtin_amdgcn_global_load_lds((const __attribute__((address_space(1))) void*)(gsrc), \
                                     (__attribute__((address_space(3))) void*)(ldst), 16, 0, 0)

// ============ prep: pack W into MFMA A-fragments, split hi/lo bf16 ============
// K-order (cg-major): step s = cg*9 + f; f=0 silu, f=1..8 rbf center k=f-1.
// Frag id per step = mt*2+h (h=0 hi, 1 lo), 1024B lane-linear:
// lane l holds W[m = mt*16+(l&15)], c = cg*32+(l>>4)*8+j  (j=0..7).
__global__ __launch_bounds__(256)
void prep_frag(const float* __restrict__ wb, const float* __restrict__ ws,
               unsigned short* __restrict__ Wf, int MT16)
{
    int idx = blockIdx.x * 256 + threadIdx.x;
    int total = 27 * MT16 * 64;
    if (idx >= total) return;
    int lane = idx & 63;
    int t = idx >> 6;
    int mt = t % MT16;
    int s = t / MT16;
    int cg = s / 9, f = s - cg * 9;
    int m = mt * 16 + (lane & 15);
    ushort8 hv, lv;
    #pragma unroll
    for (int j = 0; j < 8; ++j) {
        int c = cg * 32 + (lane >> 4) * 8 + j;
        float w = (f == 0) ? wb[m * 96 + c] : ws[(m * 96 + c) * 8 + (f - 1)];
        unsigned short hi = f2bf(w);
        unsigned short lo = f2bf(w - bf2f(hi));
        hv[j] = hi; lv[j] = lo;
    }
    size_t base = (size_t)((s * MT16 + mt) * 2) * 512 + lane * 8;
    *reinterpret_cast<ushort8*>(Wf + base) = hv;
    *reinterpret_cast<ushort8*>(Wf + base + 512) = lv;
}

// ---------------- phi via recurrence: rbf_k = e^{-(a-k)^2}, a = 1.75x+3.5 ----
// f=0: silu + init r = e^{-a^2}, du = e^{2a-1};  f>=2: r *= du, du *= e^{-2}.
template<int CG>
__device__ __forceinline__ void phi_init(const float (&xr)[24], float (&r)[8], float (&du)[8],
                                         char* dst, int lane)
{
    float ph[8];
    #pragma unroll
    for (int j = 0; j < 8; ++j) {
        float xv = xr[CG * 8 + j];
        ph[j] = __fdividef(xv, 1.f + __expf(-xv));       // silu
        float a = fmaf(xv, 1.75f, 3.5f);
        r[j] = __expf(-a * a);
        du[j] = __expf(fminf(fmaf(a, 2.f, -1.f), 80.f)); // guard overflow
    }
    uint4 w;
    w.x = cvt_pk_bf16(ph[0], ph[1]);
    w.y = cvt_pk_bf16(ph[2], ph[3]);
    w.z = cvt_pk_bf16(ph[4], ph[5]);
    w.w = cvt_pk_bf16(ph[6], ph[7]);
    *reinterpret_cast<uint4*>(dst + lane * 16) = w;
}

template<bool UPD>
__device__ __forceinline__ void phi_rbf(float (&r)[8], float (&du)[8], char* dst, int lane)
{
    if (UPD) {
        #pragma unroll
        for (int j = 0; j < 8; ++j) { r[j] *= du[j]; du[j] *= 0.1353352832366127f; }
    }
    uint4 w;
    w.x = cvt_pk_bf16(r[0], r[1]);
    w.y = cvt_pk_bf16(r[2], r[3]);
    w.z = cvt_pk_bf16(r[4], r[5]);
    w.w = cvt_pk_bf16(r[6], r[7]);
    *reinterpret_cast<uint4*>(dst + lane * 16) = w;
}

// 2 MFMA per (mt,nt): acc += Whi*phi + Wlo*phi
template<int MT>
__device__ __forceinline__ void mfma_step2(const char* sAp, const char* sBp,
                                           f32x4 (&acc)[MT][2], int lane, int wm, int wn)
{
    bf16x8 bfr[2];
    #pragma unroll
    for (int nt = 0; nt < 2; ++nt)
        bfr[nt] = *reinterpret_cast<const bf16x8*>(sBp + (wn * 2 + nt) * 1024 + lane * 16);
    #pragma unroll
    for (int mt = 0; mt < MT; ++mt) {
        bf16x8 ah = *reinterpret_cast<const bf16x8*>(
            sAp + (((wm * MT + mt) * 2 + 0) * 1024) + lane * 16);
        bf16x8 al = *reinterpret_cast<const bf16x8*>(
            sAp + (((wm * MT + mt) * 2 + 1) * 1024) + lane * 16);
        #pragma unroll
        for (int nt = 0; nt < 2; ++nt) {
            acc[mt][nt] = __builtin_amdgcn_mfma_f32_16x16x32_bf16(ah, bfr[nt], acc[mt][nt], 0, 0, 0);
            acc[mt][nt] = __builtin_amdgcn_mfma_f32_16x16x32_bf16(al, bfr[nt], acc[mt][nt], 0, 0, 0);
        }
    }
}

// ============ fused-phi split-W MFMA KAN GEMM ================================
// Block: 96 output rows (mb) x 128 cols. LDS: A dbuf 24 KiB + B dbuf 16 KiB.
// 1D grid, XCD-aware swizzle: contiguous n per XCD; the m-blocks of one n-tile
// are dispatch-adjacent on the same XCD (x + Wf L2 reuse).
// MODE 0: windowed gather (L1, out [M][139264]), grid 3264 = 8*136*3
// MODE 1: fmap gather    (L3, out [b][M][1024]), grid 1024 = 8*128
// MODE 2: lin64 gather   (L2, out [M][8192]),    grid 128  = 64*2
template<int M_TOTAL, int MODE>
__global__ __launch_bounds__(512, 6)
void kan_mfma(const float* __restrict__ xin, const float* __restrict__ token,
              const unsigned short* __restrict__ Wf, float* __restrict__ out)
{
    constexpr int NFT = (M_TOTAL / 16) * 2;   // A frags per step in Wf (all m)
    constexpr int NF = 12;                    // A frags per step this block
    constexpr int MT = 3;                     // per-wave m-tiles (wave grid 2x4)
    __shared__ char sA[2 * NF * 1024];
    __shared__ char sB[2 * 8 * 1024];

    const int tid = threadIdx.x, lane = tid & 63, wid = tid >> 6;
    const int wm = wid >> 2, wn = wid & 3;

    int n0, mb;
    if (MODE == 0) {
        int xcd = blockIdx.x & 7, idx = blockIdx.x >> 3;  // 408 per XCD
        int nloc = idx / 3; mb = idx - nloc * 3;
        n0 = (xcd * 136 + nloc) * 128;
    } else if (MODE == 1) {
        int xcd = blockIdx.x & 7;
        n0 = (xcd * 128 + (blockIdx.x >> 3)) * 128; mb = 0;
    } else {
        mb = blockIdx.x & 1; n0 = (blockIdx.x >> 1) * 128;
    }

    auto issueA = [&](int s, int buf) {
        for (int c = wid; c < NF; c += 8) {
            const unsigned short* src = Wf + (size_t)(s * NFT + mb * NF + c) * 512 + lane * 8;
            char* dst = sA + (buf * NF + c) * 1024;
            GLD_LDS16(src, dst);
        }
    };
    issueA(0, 0);

    // ---- gather the 24 x-values this thread contributes to phi -------------
    const int mycol = wid * 16 + (lane & 15);
    const int p = n0 + mycol;
    const float* gbase;
    int gstride;
    if (MODE == 0) {
        int w = p / 17, l = p - w * 17;
        if (l == 0) { gbase = token; gstride = 1; }
        else {
            int b = w >> 6, wl = w & 63;
            int wx = wl >> 3, wy = wl & 7;
            int jj = l - 1, gx = jj >> 2, gy = jj & 3;
            gbase = xin + (size_t)b * 98304 + (wx * 4 + gx) * 32 + wy * 4 + gy;
            gstride = 1024;
        }
    } else if (MODE == 1) {
        gbase = xin + (size_t)(p >> 10) * 98304 + (p & 1023);
        gstride = 1024;
    } else {
        gbase = xin + (size_t)(p >> 6) * 6144 + (p & 63);
        gstride = 64;
    }
    const int g8 = (lane >> 4) * 8;
    float xr[24];
    #pragma unroll
    for (int cg = 0; cg < 3; ++cg)
        #pragma unroll
        for (int j = 0; j < 8; ++j)
            xr[cg * 8 + j] = gbase[(size_t)(cg * 32 + g8 + j) * gstride];

    f32x4 acc[MT][2];
    #pragma unroll
    for (int mt = 0; mt < MT; ++mt)
        #pragma unroll
        for (int nt = 0; nt < 2; ++nt) {
            f32x4 z = {0.f, 0.f, 0.f, 0.f};
            acc[mt][nt] = z;
        }

    float rr[8], du[8];
    // phi for s=0 (cg=0, f=0) into sB buffer 0 (frag wid = cols wid*16..+15)
    phi_init<0>(xr, rr, du, sB + wid * 1024, lane);

#define STEP(S) {                                                               \
        constexpr int s_ = (S);                                                 \
        constexpr int sbuf_ = s_ & 1;                                           \
        __syncthreads();                                                        \
        if (s_ + 1 < 27) issueA(s_ + 1, (s_ + 1) & 1);                          \
        mfma_step2<MT>(sA + sbuf_ * NF * 1024, sB + sbuf_ * 8 * 1024,           \
                       acc, lane, wm, wn);                                      \
        if (s_ + 1 < 27) {                                                      \
            char* dst_ = sB + ((sbuf_ ^ 1) * 8 + wid) * 1024;                   \
            if ((s_ + 1) % 9 == 0)                                              \
                phi_init<(s_ + 1) / 9>(xr, rr, du, dst_, lane);                 \
            else                                                                \
                phi_rbf<((s_ + 1) % 9) != 1>(rr, du, dst_, lane);               \
        }                                                                       \
    }
#define STEP9(B) STEP(B+0) STEP(B+1) STEP(B+2) STEP(B+3) STEP(B+4) \
                 STEP(B+5) STEP(B+6) STEP(B+7) STEP(B+8)
    STEP9(0) STEP9(9) STEP9(18)
#undef STEP9
#undef STEP

    // ---- epilogue ----
    #pragma unroll
    for (int mt = 0; mt < MT; ++mt) {
        const int row = mb * 96 + wm * 48 + mt * 16 + (lane >> 4) * 4;
        #pragma unroll
        for (int nt = 0; nt < 2; ++nt) {
            const int col_l = wn * 32 + nt * 16 + (lane & 15);
            #pragma unroll
            for (int r = 0; r < 4; ++r) {
                float v = acc[mt][nt][r];
                if (MODE == 0)
                    out[(size_t)(row + r) * 139264 + n0 + col_l] = v;
                else if (MODE == 1) {
                    int col = n0 + col_l;
                    out[(size_t)(col >> 10) * 98304 + (size_t)(row + r) * 1024 + (col & 1023)] = v;
                } else {
                    out[(size_t)(row + r) * 8192 + n0 + col_l] = v;
                }
            }
        }
    }
}

// ---------------- window feature-attention (32x32, contract 17 tokens) -------
__global__ __launch_bounds__(256)
void attn1(const float* __restrict__ qkv, float* __restrict__ gt, float* __restrict__ gf)
{
    int w = blockIdx.x;
    int tid = threadIdx.x;
    __shared__ float sq[3][32][17];
    __shared__ float sk[3][32][17];
    __shared__ float sv[3][32][17];
    __shared__ float sa[3][32][33];
    const size_t N = 139264;

    for (int e = tid; e < 288 * 17; e += 256) {
        int row = e / 17, l = e - row * 17;
        float v = qkv[(size_t)row * N + (size_t)w * 17 + l];
        int sec = row / 96, ch = row - sec * 96;
        int h = ch >> 5, d = ch & 31;
        if (sec == 0)      sq[h][d][l] = v * SCALE;
        else if (sec == 1) sk[h][d][l] = v;
        else               sv[h][d][l] = v;
    }
    __syncthreads();
    for (int e = tid; e < 3 * 32 * 32; e += 256) {
        int h = e >> 10, r = e & 1023, i = r >> 5, j = r & 31;
        float s = 0.f;
        #pragma unroll
        for (int l = 0; l < 17; ++l) s += sq[h][i][l] * sk[h][j][l];
        sa[h][i][j] = s;
    }
    __syncthreads();
    if (tid < 96) {
        int h = tid >> 5, i = tid & 31;
        float m = -1e30f;
        for (int j = 0; j < 32; ++j) m = fmaxf(m, sa[h][i][j]);
        float sum = 0.f;
        for (int j = 0; j < 32; ++j) { float e_ = __expf(sa[h][i][j] - m); sa[h][i][j] = e_; sum += e_; }
        float inv = 1.f / sum;
        for (int j = 0; j < 32; ++j) sa[h][i][j] *= inv;
    }
    __syncthreads();
    int b = w >> 6, wl = w & 63;
    for (int e = tid; e < 3 * 17 * 32; e += 256) {
        int h = e / 544, r = e - h * 544, l = r >> 5, i = r & 31;
        float s = 0.f;
        #pragma unroll
        for (int j = 0; j < 32; ++j) s += sa[h][i][j] * sv[h][j][l];
        if (l == 0) gt[(((size_t)b * 3 + h) * 64 + wl) * 32 + i] = s;
        else        gf[((((size_t)b * 3 + h) * 64 + wl) * 16 + (l - 1)) * 32 + i] = s;
    }
}

// ---------------- LN (over 32) + exact GELU -> hh (b, 96, 64) ----------------
__global__ __launch_bounds__(256)
void ln_gelu(const float* __restrict__ gt, const float* __restrict__ lng,
             const float* __restrict__ lnb, float* __restrict__ hh)
{
    int row = blockIdx.x * 8 + (threadIdx.x >> 5);
    int d = threadIdx.x & 31;
    float x = gt[(size_t)row * 32 + d];
    float s = x, s2 = x * x;
    #pragma unroll
    for (int m = 16; m >= 1; m >>= 1) { s += __shfl_xor(s, m, 32); s2 += __shfl_xor(s2, m, 32); }
    float mu = s * (1.f / 32.f);
    float var = s2 * (1.f / 32.f) - mu * mu;
    float h = (x - mu) * rsqrtf(var + EPS) * lng[d] + lnb[d];
    float g = 0.5f * h * (1.f + erff(h * 0.70710678118654752f));
    int b = row / 192, r = row - b * 192;
    int hd = r >> 6, wl = r & 63;
    hh[((size_t)b * 96 + hd * 32 + d) * 64 + wl] = g;
}

// ---------------- window-token attention: dots + softmax ---------------------
__global__ __launch_bounds__(256)
void attn2a(const float* __restrict__ qk, float* __restrict__ wattn)
{
    int bh = blockIdx.x;
    int b = bh / 3, h = bh - b * 3;
    __shared__ float swq[64][33];
    __shared__ float swk[64][33];
    __shared__ float sd[64][65];
    int tid = threadIdx.x;
    for (int e = tid; e < 2048; e += 256) {
        int d = e >> 6, i = e & 63;
        swq[i][d] = qk[((size_t)h * 64 + d) * 8192 + b * 64 + i] * SCALE;
        swk[i][d] = qk[((size_t)h * 64 + 32 + d) * 8192 + b * 64 + i];
    }
    __syncthreads();
    for (int e = tid; e < 4096; e += 256) {
        int i = e >> 6, j = e & 63;
        float s = 0.f;
        #pragma unroll
        for (int d = 0; d < 32; ++d) s += swq[i][d] * swk[j][d];
        sd[i][j] = s;
    }
    __syncthreads();
    if (tid < 64) {
        float m = -1e30f;
        for (int j = 0; j < 64; ++j) m = fmaxf(m, sd[tid][j]);
        float sum = 0.f;
        for (int j = 0; j < 64; ++j) { float e_ = __expf(sd[tid][j] - m); sd[tid][j] = e_; sum += e_; }
        float inv = 1.f / sum;
        for (int j = 0; j < 64; ++j) sd[tid][j] *= inv;
    }
    __syncthreads();
    for (int e = tid; e < 4096; e += 256)
        wattn[(size_t)bh * 4096 + e] = sd[e >> 6][e & 63];
}

// ---------------- agg = attn @ gf, scatter to fmap (b,96,32,32) --------------
__global__ __launch_bounds__(256)
void attn2b(const float* __restrict__ wattn, const float* __restrict__ gf,
            float* __restrict__ fmap)
{
    int blk = blockIdx.x;
    int ct = blk & 3, bh = blk >> 2;
    int b = bh / 3, h = bh - b * 3;
    __shared__ float sa[64][65];
    __shared__ float sg[64][129];
    int tid = threadIdx.x;
    for (int e = tid; e < 4096; e += 256) sa[e >> 6][e & 63] = wattn[(size_t)bh * 4096 + e];
    for (int e = tid; e < 8192; e += 256) {
        int j = e >> 7, c = e & 127;
        sg[j][c] = gf[((size_t)bh * 64 + j) * 512 + ct * 128 + c];
    }
    __syncthreads();
    int txc = tid & 31, tyi = tid >> 5;
    float acc[8][4];
    #pragma unroll
    for (int ii = 0; ii < 8; ++ii)
        #pragma unroll
        for (int c = 0; c < 4; ++c) acc[ii][c] = 0.f;
    for (int j = 0; j < 64; ++j) {
        float g0[4];
        #pragma unroll
        for (int c = 0; c < 4; ++c) g0[c] = sg[j][txc + c * 32];
        #pragma unroll
        for (int ii = 0; ii < 8; ++ii) {
            float a = sa[tyi + ii * 8][j];
            #pragma unroll
            for (int c = 0; c < 4; ++c) acc[ii][c] += a * g0[c];
        }
    }
    __syncthreads();
    #pragma unroll
    for (int ii = 0; ii < 8; ++ii)
        #pragma unroll
        for (int c = 0; c < 4; ++c)
            sg[tyi + ii * 8][txc + c * 32] = acc[ii][c];
    __syncthreads();
    for (int e = tid; e < 8192; e += 256) {
        int d = e >> 8;
        int nx = (e >> 5) & 7;
        int cp = e & 31;
        int ny = cp >> 2, gy = cp & 3;
        float v = sg[nx * 8 + ny][gy * 32 + d];
        fmap[(((size_t)b * 96 + h * 32 + d) * 32 + nx * 4 + ct) * 32 + cp] = v;
    }
}

// -----------------------------------------------------------------------------
extern "C" void kernel_launch(void* const* d_in, const int* in_sizes, int n_in,
                              void* d_out, int out_size, void* d_ws, size_t ws_size,
                              hipStream_t stream)
{
    const float* x      = (const float*)d_in[0];
    const float* tok    = (const float*)d_in[1];
    const float* qkv_wb = (const float*)d_in[2];
    const float* qkv_ws = (const float*)d_in[3];
    const float* lng    = (const float*)d_in[4];
    const float* lnb    = (const float*)d_in[5];
    const float* gt_wb  = (const float*)d_in[6];
    const float* gt_ws  = (const float*)d_in[7];
    const float* out_wb = (const float*)d_in[8];
    const float* out_ws = (const float*)d_in[9];
    float* out = (float*)d_out;
    float* ws  = (float*)d_ws;

    const size_t OFF_QKV   = 0;            // 40,108,032 floats
    const size_t OFF_FMAP  = 0;            // reuses dead qkv region
    const size_t OFF_WATTN = 12582912;
    const size_t OFF_WF2   = 40108032;     // 165,888 floats (27*24*512 shorts)
    const size_t OFF_GT    = OFF_WF2 + 165888;
    const size_t OFF_GF    = OFF_GT + 786432;
    const size_t OFF_HH    = OFF_GF + 12582912;
    const size_t OFF_QK    = OFF_HH + 786432;
    const size_t OFF_WF1   = OFF_QK + 1572864;    // 248,832 floats
    const size_t OFF_WF3   = OFF_WF1 + 248832;    // 82,944 floats
    const size_t TOTAL     = OFF_WF3 + 82944;     // 56,334,336 floats
    if (ws_size < TOTAL * sizeof(float)) return;

    unsigned short* wf1 = (unsigned short*)(ws + OFF_WF1);
    unsigned short* wf2 = (unsigned short*)(ws + OFF_WF2);
    unsigned short* wf3 = (unsigned short*)(ws + OFF_WF3);

    prep_frag<<<(27 * 18 * 64 + 255) / 256, 256, 0, stream>>>(qkv_wb, qkv_ws, wf1, 18);
    prep_frag<<<(27 * 12 * 64 + 255) / 256, 256, 0, stream>>>(gt_wb,  gt_ws,  wf2, 12);
    prep_frag<<<(27 * 6 * 64 + 255) / 256, 256, 0, stream>>>(out_wb, out_ws, wf3, 6);

    kan_mfma<288, 0><<<3264, 512, 0, stream>>>(x, tok, wf1, ws + OFF_QKV);
    attn1<<<8192, 256, 0, stream>>>(ws + OFF_QKV, ws + OFF_GT, ws + OFF_GF);
    ln_gelu<<<3072, 256, 0, stream>>>(ws + OFF_GT, lng, lnb, ws + OFF_HH);
    kan_mfma<192, 2><<<128, 512, 0, stream>>>(ws + OFF_HH, nullptr, wf2, ws + OFF_QK);
    attn2a<<<384, 256, 0, stream>>>(ws + OFF_QK, ws + OFF_WATTN);
    attn2b<<<1536, 256, 0, stream>>>(ws + OFF_WATTN, ws + OFF_GF, ws + OFF_FMAP);
    kan_mfma<96, 1><<<1024, 512, 0, stream>>>(ws + OFF_FMAP, nullptr, wf3, out);
}